// Round 2
// baseline (1663.116 us; speedup 1.0000x reference)
//
#include <hip/hip_runtime.h>
#include <stdint.h>

#define N_NODES 100000
#define N_EDGES 3200000
#define BN      64                  // nodes per dst-bucket
#define NB      1563                // ceil(N_NODES / BN)
#define BLOCK   256

// ---------------------------------------------------------------------------
// Stage 0: pad x (stride 6 -> 8, zero pads) + zero bucket counters
// ---------------------------------------------------------------------------
__global__ void pad_x_kernel(const float* __restrict__ x, float* __restrict__ xpad,
                             int* __restrict__ bcount) {
    int i = blockIdx.x * blockDim.x + threadIdx.x;
    if (i < NB) bcount[i] = 0;
    if (i < N_NODES) {
        const float* xr = x + (size_t)i * 6;
        float4 a, b;
        a.x = xr[0]; a.y = xr[1]; a.z = xr[2]; a.w = xr[3];
        b.x = xr[4]; b.y = xr[5]; b.z = 0.f; b.w = 0.f;
        float4* o = (float4*)(xpad + (size_t)i * 8);
        o[0] = a; o[1] = b;
    }
}

// ---------------------------------------------------------------------------
// Stage 1: histogram of edges per bucket (LDS-staged to avoid 3.2M global atomics)
// ---------------------------------------------------------------------------
__global__ void hist_kernel(const int* __restrict__ dst, int* __restrict__ bcount) {
    __shared__ int h[NB];
    for (int i = threadIdx.x; i < NB; i += BLOCK) h[i] = 0;
    __syncthreads();
    int stride = gridDim.x * blockDim.x;
    for (int e = blockIdx.x * blockDim.x + threadIdx.x; e < N_EDGES; e += stride)
        atomicAdd(&h[dst[e] >> 6], 1);
    __syncthreads();
    for (int i = threadIdx.x; i < NB; i += BLOCK) {
        int c = h[i];
        if (c) atomicAdd(&bcount[i], c);
    }
}

// ---------------------------------------------------------------------------
// Stage 2: exclusive scan of 1563 bucket counts (one wg, 2-level)
// ---------------------------------------------------------------------------
#define SCAN_T   1024
#define SCAN_PER 2            // covers 2048 >= NB
__global__ void scan_kernel(const int* __restrict__ cnt, int* __restrict__ bstart,
                            int* __restrict__ gcur) {
    __shared__ int part[SCAN_T];
    int t = threadIdx.x;
    int local[SCAN_PER];
    int s = 0;
    #pragma unroll
    for (int i = 0; i < SCAN_PER; ++i) {
        int idx = t * SCAN_PER + i;
        int v = (idx < NB) ? cnt[idx] : 0;
        local[i] = s;
        s += v;
    }
    part[t] = s;
    __syncthreads();
    for (int off = 1; off < SCAN_T; off <<= 1) {
        int v = (t >= off) ? part[t - off] : 0;
        __syncthreads();
        part[t] += v;
        __syncthreads();
    }
    int excl = part[t] - s;
    #pragma unroll
    for (int i = 0; i < SCAN_PER; ++i) {
        int idx = t * SCAN_PER + i;
        if (idx < NB) {
            int b0 = excl + local[i];
            bstart[idx] = b0;
            gcur[idx]   = b0;
        }
    }
}

// ---------------------------------------------------------------------------
// Stage 3: fill bucket-grouped edge records.
// rec.x = src (17 bits) | dst_local (6 bits) << 17 ; rec.y = weight bits.
// Write frontier = 1563 append streams (~100 KB of hot lines, L2-resident)
// instead of 100k node rows -> kills the 198 MB write amplification.
// ---------------------------------------------------------------------------
__global__ void fill_kernel(const int* __restrict__ src, const int* __restrict__ dst,
                            const float* __restrict__ w, int* __restrict__ gcur,
                            uint2* __restrict__ rec) {
    int e = blockIdx.x * blockDim.x + threadIdx.x;
    if (e < N_EDGES) {
        int d = dst[e];
        int b = d >> 6;
        int pos = atomicAdd(&gcur[b], 1);
        uint2 r;
        r.x = (uint32_t)src[e] | ((uint32_t)(d & 63) << 17);
        r.y = __float_as_uint(w[e]);
        rec[pos] = r;
    }
}

// ---------------------------------------------------------------------------
// Fused layer, one workgroup per bucket:
//   edge phase : edge-parallel gather x[src] (float4), LDS-atomic accumulate
//                into agg[64][SIN]  (random rows -> ~2 lanes/bank, free)
//   dense phase: per node  out = agg@Wrel + b + x@Wroot, relu / softmax
// ---------------------------------------------------------------------------
template<int DIN, int SIN, int DOUT, int SOUT, bool LAST>
__global__ void layer_kernel(const float* __restrict__ xin,
                             const uint2* __restrict__ rec,
                             const int* __restrict__ bstart,
                             const int* __restrict__ bcount,
                             const float* __restrict__ wrel,
                             const float* __restrict__ brel,
                             const float* __restrict__ wroot,
                             float* __restrict__ xout) {
    __shared__ float agg[BN * SIN];
    __shared__ float s_wrel[DIN * DOUT];
    __shared__ float s_wroot[DIN * DOUT];
    __shared__ float s_b[DOUT];

    for (int t = threadIdx.x; t < BN * SIN; t += BLOCK) agg[t] = 0.f;
    for (int t = threadIdx.x; t < DIN * DOUT; t += BLOCK) {
        s_wrel[t]  = wrel[t];
        s_wroot[t] = wroot[t];
    }
    if (threadIdx.x < DOUT) s_b[threadIdx.x] = brel[threadIdx.x];
    __syncthreads();

    const int b = blockIdx.x;
    const int s = bstart[b];
    const int e = s + bcount[b];
    constexpr int NV = SIN / 4;

    for (int k = s + threadIdx.x; k < e; k += BLOCK) {
        uint2 r = rec[k];
        int src = (int)(r.x & 0x1FFFF);
        int dl  = (int)(r.x >> 17);
        float w = __uint_as_float(r.y);
        const float4* xs = (const float4*)(xin + (size_t)src * SIN);
        float4 xv[NV];
        #pragma unroll
        for (int v = 0; v < NV; ++v) xv[v] = xs[v];
        const float* xf = (const float*)xv;
        float* arow = &agg[dl * SIN];
        #pragma unroll
        for (int i = 0; i < DIN; ++i) atomicAdd(&arow[i], w * xf[i]);
    }
    __syncthreads();

    const int r = threadIdx.x;
    if (r < BN) {
        int node = b * BN + r;
        if (node < N_NODES) {
            const float* accf  = &agg[r * SIN];
            const float* selff = xin + (size_t)node * SIN;
            float out[DOUT];
            #pragma unroll
            for (int j = 0; j < DOUT; ++j) out[j] = s_b[j];
            #pragma unroll
            for (int i = 0; i < DIN; ++i) {
                float a  = accf[i];
                float sf = selff[i];
                #pragma unroll
                for (int j = 0; j < DOUT; ++j)
                    out[j] += a * s_wrel[i * DOUT + j] + sf * s_wroot[i * DOUT + j];
            }
            if (LAST) {
                float m = out[0];
                #pragma unroll
                for (int j = 1; j < DOUT; ++j) m = fmaxf(m, out[j]);
                float sum = 0.f;
                #pragma unroll
                for (int j = 0; j < DOUT; ++j) { out[j] = __expf(out[j] - m); sum += out[j]; }
                float inv = 1.f / sum;
                #pragma unroll
                for (int j = 0; j < DOUT; ++j) xout[(size_t)node * SOUT + j] = out[j] * inv;
            } else {
                #pragma unroll
                for (int j = 0; j < DOUT; ++j)
                    xout[(size_t)node * SOUT + j] = fmaxf(out[j], 0.f);
                #pragma unroll
                for (int j = DOUT; j < SOUT; ++j)
                    xout[(size_t)node * SOUT + j] = 0.f;   // zero pads for next layer's float4 gather
            }
        }
    }
}

// ---------------------------------------------------------------------------

extern "C" void kernel_launch(void* const* d_in, const int* in_sizes, int n_in,
                              void* d_out, int out_size, void* d_ws, size_t ws_size,
                              hipStream_t stream) {
    const float* x  = (const float*)d_in[0];
    const int*   ei = (const int*)d_in[1];
    const float* ew = (const float*)d_in[2];
    const float* wrel[5]  = { (const float*)d_in[3], (const float*)d_in[6],
                              (const float*)d_in[9], (const float*)d_in[12],
                              (const float*)d_in[15] };
    const float* brel[5]  = { (const float*)d_in[4], (const float*)d_in[7],
                              (const float*)d_in[10], (const float*)d_in[13],
                              (const float*)d_in[16] };
    const float* wroot[5] = { (const float*)d_in[5], (const float*)d_in[8],
                              (const float*)d_in[11], (const float*)d_in[14],
                              (const float*)d_in[17] };

    char* ws = (char*)d_ws;
    size_t off = 0;
    auto alloc = [&](size_t bytes) -> void* {
        void* p = ws + off;
        off += (bytes + 255) & ~(size_t)255;
        return p;
    };
    int*   bcount = (int*)alloc((size_t)NB * 4);
    int*   bstart = (int*)alloc((size_t)NB * 4);
    int*   gcur   = (int*)alloc((size_t)NB * 4);
    uint2* rec    = (uint2*)alloc((size_t)N_EDGES * 8);
    float* bufA   = (float*)alloc((size_t)N_NODES * 20 * 4);
    float* bufB   = (float*)alloc((size_t)N_NODES * 20 * 4);

    const int* srcv = ei;            // edge_index row 0
    const int* dstv = ei + N_EDGES;  // edge_index row 1

    const int gN = (N_NODES + BLOCK - 1) / BLOCK;
    const int gE = (N_EDGES + BLOCK - 1) / BLOCK;

    pad_x_kernel<<<gN, BLOCK, 0, stream>>>(x, bufA, bcount);
    hist_kernel <<<256, BLOCK, 0, stream>>>(dstv, bcount);
    scan_kernel <<<1, SCAN_T, 0, stream>>>(bcount, bstart, gcur);
    fill_kernel <<<gE, BLOCK, 0, stream>>>(srcv, dstv, ew, gcur, rec);

    // dims: 6 -> 20 -> 15 -> 10 -> 5 -> 2 (softmax)
    layer_kernel< 6,  8, 20, 20, false><<<NB, BLOCK, 0, stream>>>(
        bufA, rec, bstart, bcount, wrel[0], brel[0], wroot[0], bufB);
    layer_kernel<20, 20, 15, 16, false><<<NB, BLOCK, 0, stream>>>(
        bufB, rec, bstart, bcount, wrel[1], brel[1], wroot[1], bufA);
    layer_kernel<15, 16, 10, 12, false><<<NB, BLOCK, 0, stream>>>(
        bufA, rec, bstart, bcount, wrel[2], brel[2], wroot[2], bufB);
    layer_kernel<10, 12,  5,  8, false><<<NB, BLOCK, 0, stream>>>(
        bufB, rec, bstart, bcount, wrel[3], brel[3], wroot[3], bufA);
    layer_kernel< 5,  8,  2,  2, true ><<<NB, BLOCK, 0, stream>>>(
        bufA, rec, bstart, bcount, wrel[4], brel[4], wroot[4], (float*)d_out);
}

// Round 3
// 494.651 us; speedup vs baseline: 3.3622x; 3.3622x over previous
//
#include <hip/hip_runtime.h>
#include <stdint.h>

#define N_NODES 100000
#define N_EDGES 3200000
#define BN      64                    // nodes per dst-bucket
#define NB      1563                  // ceil(N_NODES / BN)
#define NCHUNK  256                   // edge chunks (one block each)
#define CH      (N_EDGES / NCHUNK)    // 12500 edges per chunk (exact)
#define BLOCK   256

// ---------------------------------------------------------------------------
// Stage 0: pad x (stride 6 -> 8, zero pads) for float4 gathers in layer 0
// ---------------------------------------------------------------------------
__global__ void pad_x_kernel(const float* __restrict__ x, float* __restrict__ xpad) {
    int i = blockIdx.x * blockDim.x + threadIdx.x;
    if (i < N_NODES) {
        const float* xr = x + (size_t)i * 6;
        float4 a, b;
        a.x = xr[0]; a.y = xr[1]; a.z = xr[2]; a.w = xr[3];
        b.x = xr[4]; b.y = xr[5]; b.z = 0.f; b.w = 0.f;
        float4* o = (float4*)(xpad + (size_t)i * 8);
        o[0] = a; o[1] = b;
    }
}

// ---------------------------------------------------------------------------
// Stage 1: per-chunk bucket histogram (LDS-staged, coalesced global writes)
// ---------------------------------------------------------------------------
__global__ void hist_kernel(const int* __restrict__ dst, int* __restrict__ hist_g) {
    __shared__ int h[NB];
    for (int b = threadIdx.x; b < NB; b += BLOCK) h[b] = 0;
    __syncthreads();
    const int k0 = blockIdx.x * CH;
    for (int k = threadIdx.x; k < CH; k += BLOCK)
        atomicAdd(&h[dst[k0 + k] >> 6], 1);
    __syncthreads();
    for (int b = threadIdx.x; b < NB; b += BLOCK)
        hist_g[blockIdx.x * NB + b] = h[b];
}

// ---------------------------------------------------------------------------
// Stage 2a: per-bucket exclusive scan over the 256 chunk counts (1 wave/bucket)
// off_g[c][b] = sum_{c'<c} hist_g[c'][b]   (relative to bucket start)
// tot[b]     = total records in bucket b
// ---------------------------------------------------------------------------
__global__ void chunkscan_kernel(const int* __restrict__ hist_g,
                                 int* __restrict__ off_g, int* __restrict__ tot) {
    int w    = (blockIdx.x * blockDim.x + threadIdx.x) >> 6;  // global wave = bucket
    int lane = threadIdx.x & 63;
    if (w >= NB) return;
    int v[4];
    int ls = 0;
    const int cbase = lane * 4;
    #pragma unroll
    for (int i = 0; i < 4; ++i) { v[i] = hist_g[(cbase + i) * NB + w]; ls += v[i]; }
    int run = ls;
    #pragma unroll
    for (int d = 1; d < 64; d <<= 1) {
        int u = __shfl_up(run, d);
        if (lane >= d) run += u;
    }
    int acc = run - ls;   // exclusive over lanes
    #pragma unroll
    for (int i = 0; i < 4; ++i) { off_g[(cbase + i) * NB + w] = acc; acc += v[i]; }
    if (lane == 63) tot[w] = acc;
}

// ---------------------------------------------------------------------------
// Stage 2b: exclusive scan of 1563 bucket totals (one wg, 2-level)
// ---------------------------------------------------------------------------
#define SCAN_T   1024
#define SCAN_PER 2
__global__ void scan_kernel(const int* __restrict__ cnt, int* __restrict__ bstart) {
    __shared__ int part[SCAN_T];
    int t = threadIdx.x;
    int local[SCAN_PER];
    int s = 0;
    #pragma unroll
    for (int i = 0; i < SCAN_PER; ++i) {
        int idx = t * SCAN_PER + i;
        int v = (idx < NB) ? cnt[idx] : 0;
        local[i] = s;
        s += v;
    }
    part[t] = s;
    __syncthreads();
    for (int off = 1; off < SCAN_T; off <<= 1) {
        int v = (t >= off) ? part[t - off] : 0;
        __syncthreads();
        part[t] += v;
        __syncthreads();
    }
    int excl = part[t] - s;
    #pragma unroll
    for (int i = 0; i < SCAN_PER; ++i) {
        int idx = t * SCAN_PER + i;
        if (idx < NB) bstart[idx] = excl + local[i];
    }
}

// ---------------------------------------------------------------------------
// Stage 3: scatter pass 1 — bucket-partition edges. Zero global atomics;
// every (chunk,bucket) output run is exclusively owned by this block.
// rec.x = src (17b) | dst_local (6b) << 17 ; rec.y = weight bits.
// ---------------------------------------------------------------------------
__global__ void scatter1_kernel(const int* __restrict__ src, const int* __restrict__ dst,
                                const float* __restrict__ w,
                                const int* __restrict__ bstart, const int* __restrict__ off_g,
                                uint2* __restrict__ rec1) {
    __shared__ int cur[NB];
    const int c = blockIdx.x;
    for (int b = threadIdx.x; b < NB; b += BLOCK)
        cur[b] = bstart[b] + off_g[c * NB + b];
    __syncthreads();
    const int k0 = c * CH;
    for (int k = threadIdx.x; k < CH; k += BLOCK) {
        int e = k0 + k;
        int d = dst[e];
        int b = d >> 6;
        int pos = atomicAdd(&cur[b], 1);   // LDS atomic only
        uint2 r;
        r.x = (uint32_t)src[e] | ((uint32_t)(d & 63) << 17);
        r.y = __float_as_uint(w[e]);
        rec1[pos] = r;
    }
}

// ---------------------------------------------------------------------------
// Stage 4: scatter pass 2 — sort each ~2048-record bucket to node granularity.
// One block per bucket; output range exclusively owned; emits row_start/cnt.
// ---------------------------------------------------------------------------
__global__ void scatter2_kernel(const uint2* __restrict__ rec1,
                                const int* __restrict__ bstart, const int* __restrict__ tot,
                                uint2* __restrict__ rec2,
                                int* __restrict__ row_start, int* __restrict__ cnt) {
    __shared__ int h[BN];
    __shared__ int cur[BN];
    const int b  = blockIdx.x;
    const int s0 = bstart[b];
    const int n  = tot[b];
    if (threadIdx.x < BN) h[threadIdx.x] = 0;
    __syncthreads();
    for (int k = threadIdx.x; k < n; k += BLOCK)
        atomicAdd(&h[rec1[s0 + k].x >> 17], 1);
    __syncthreads();
    if (threadIdx.x < BN) {   // wave 0: exclusive scan of 64 bins
        int v = h[threadIdx.x];
        int run = v;
        #pragma unroll
        for (int d = 1; d < 64; d <<= 1) {
            int u = __shfl_up(run, d);
            if (threadIdx.x >= d) run += u;
        }
        int excl = run - v;
        cur[threadIdx.x] = excl;
        int node = b * BN + threadIdx.x;
        if (node < N_NODES) { row_start[node] = s0 + excl; cnt[node] = v; }
    }
    __syncthreads();
    for (int k = threadIdx.x; k < n; k += BLOCK) {
        uint2 r = rec1[s0 + k];
        int dl = (int)(r.x >> 17);
        int pos = s0 + atomicAdd(&cur[dl], 1);
        rec2[pos] = r;
    }
}

// ---------------------------------------------------------------------------
// Layer 0 (din=6 < dout=20: aggregate pre-transform). 4 lanes per node;
// each lane takes every 4th edge; butterfly shfl-reduce; lanes split the
// 20 outputs (5 each) for the dense epilogue.
// ---------------------------------------------------------------------------
__global__ void layer0_kernel(const float* __restrict__ xpad,
                              const uint2* __restrict__ rec,
                              const int* __restrict__ row_start, const int* __restrict__ cnt,
                              const float* __restrict__ wrel, const float* __restrict__ brel,
                              const float* __restrict__ wroot,
                              float* __restrict__ out) {
    __shared__ float s_wrel[6 * 20];
    __shared__ float s_wroot[6 * 20];
    __shared__ float s_b[20];
    for (int t = threadIdx.x; t < 120; t += BLOCK) {
        s_wrel[t]  = wrel[t];
        s_wroot[t] = wroot[t];
    }
    if (threadIdx.x < 20) s_b[threadIdx.x] = brel[threadIdx.x];
    __syncthreads();

    int t = blockIdx.x * blockDim.x + threadIdx.x;
    int node = t >> 2;
    int q    = t & 3;
    if (node >= N_NODES) return;

    float4 a0 = make_float4(0.f, 0.f, 0.f, 0.f);
    float4 a1 = make_float4(0.f, 0.f, 0.f, 0.f);
    const int s = row_start[node];
    const int e = s + cnt[node];
    for (int k = s + q; k < e; k += 4) {
        uint2 r = rec[k];
        float w = __uint_as_float(r.y);
        const float4* xs = (const float4*)(xpad + (size_t)(r.x & 0x1FFFF) * 8);
        float4 x0 = xs[0], x1 = xs[1];
        a0.x += w * x0.x; a0.y += w * x0.y; a0.z += w * x0.z; a0.w += w * x0.w;
        a1.x += w * x1.x; a1.y += w * x1.y;
        (void)x1;
    }
    float agg[6] = { a0.x, a0.y, a0.z, a0.w, a1.x, a1.y };
    #pragma unroll
    for (int i = 0; i < 6; ++i) {
        agg[i] += __shfl_xor(agg[i], 1);
        agg[i] += __shfl_xor(agg[i], 2);
    }
    const float4* xsf = (const float4*)(xpad + (size_t)node * 8);
    float4 x0 = xsf[0], x1 = xsf[1];
    float xv[6] = { x0.x, x0.y, x0.z, x0.w, x1.x, x1.y };

    const int j0 = q * 5;
    #pragma unroll
    for (int jj = 0; jj < 5; ++jj) {
        int j = j0 + jj;
        float o = s_b[j];
        #pragma unroll
        for (int i = 0; i < 6; ++i)
            o += agg[i] * s_wrel[i * 20 + j] + xv[i] * s_wroot[i * 20 + j];
        out[(size_t)node * 20 + j] = fmaxf(o, 0.f);
    }
}

// ---------------------------------------------------------------------------
// Layers 1..4: dense pre-kernel (node-parallel):
//   p     = x @ Wrel          [N, SP]  (padded to SP, pads = 0; gathered later)
//   oinit = x @ Wroot + b     [N, DOUT]
// ---------------------------------------------------------------------------
template<int DIN, int DOUT, int SP>
__global__ void dense_kernel(const float* __restrict__ xin,
                             const float* __restrict__ wrel, const float* __restrict__ brel,
                             const float* __restrict__ wroot,
                             float* __restrict__ p, float* __restrict__ oinit) {
    __shared__ float s_wrel[DIN * DOUT];
    __shared__ float s_wroot[DIN * DOUT];
    __shared__ float s_b[DOUT];
    for (int t = threadIdx.x; t < DIN * DOUT; t += BLOCK) {
        s_wrel[t]  = wrel[t];
        s_wroot[t] = wroot[t];
    }
    if (threadIdx.x < DOUT) s_b[threadIdx.x] = brel[threadIdx.x];
    __syncthreads();

    int node = blockIdx.x * blockDim.x + threadIdx.x;
    if (node >= N_NODES) return;

    float xv[DIN];
    #pragma unroll
    for (int i = 0; i < DIN; ++i) xv[i] = xin[(size_t)node * DIN + i];

    float pv[DOUT], ov[DOUT];
    #pragma unroll
    for (int j = 0; j < DOUT; ++j) { pv[j] = 0.f; ov[j] = s_b[j]; }
    #pragma unroll
    for (int i = 0; i < DIN; ++i) {
        float xi = xv[i];
        #pragma unroll
        for (int j = 0; j < DOUT; ++j) {
            pv[j] += xi * s_wrel[i * DOUT + j];
            ov[j] += xi * s_wroot[i * DOUT + j];
        }
    }
    #pragma unroll
    for (int j = 0; j < DOUT; ++j) {
        p[(size_t)node * SP + j]      = pv[j];
        oinit[(size_t)node * DOUT + j] = ov[j];
    }
    #pragma unroll
    for (int j = DOUT; j < SP; ++j) p[(size_t)node * SP + j] = 0.f;
}

// ---------------------------------------------------------------------------
// Layers 1..4: gather kernel (post-transform aggregation in DOUT dim).
// 4 lanes/node, butterfly reduce, lanes split outputs. LAST fuses softmax.
// ---------------------------------------------------------------------------
template<int DOUT, int SP, bool LAST>
__global__ void gather_kernel(const float* __restrict__ p, const float* __restrict__ oinit,
                              const uint2* __restrict__ rec,
                              const int* __restrict__ row_start, const int* __restrict__ cnt,
                              float* __restrict__ out) {
    int t = blockIdx.x * blockDim.x + threadIdx.x;
    int node = t >> 2;
    int q    = t & 3;
    if (node >= N_NODES) return;

    constexpr int NV = SP / 4;
    float4 acc[NV];
    #pragma unroll
    for (int v = 0; v < NV; ++v) acc[v] = make_float4(0.f, 0.f, 0.f, 0.f);

    const int s = row_start[node];
    const int e = s + cnt[node];
    for (int k = s + q; k < e; k += 4) {
        uint2 r = rec[k];
        float w = __uint_as_float(r.y);
        const float4* ps = (const float4*)(p + (size_t)(r.x & 0x1FFFF) * SP);
        #pragma unroll
        for (int v = 0; v < NV; ++v) {
            float4 pv = ps[v];
            acc[v].x += w * pv.x;
            acc[v].y += w * pv.y;
            acc[v].z += w * pv.z;
            acc[v].w += w * pv.w;
        }
    }
    float* af = (float*)acc;
    #pragma unroll
    for (int i = 0; i < SP; ++i) {
        af[i] += __shfl_xor(af[i], 1);
        af[i] += __shfl_xor(af[i], 2);
    }

    if (LAST) {
        if (q == 0) {
            float o0 = af[0] + oinit[(size_t)node * 2 + 0];
            float o1 = af[1] + oinit[(size_t)node * 2 + 1];
            float m = fmaxf(o0, o1);
            float e0 = __expf(o0 - m), e1 = __expf(o1 - m);
            float inv = 1.f / (e0 + e1);
            out[(size_t)node * 2 + 0] = e0 * inv;
            out[(size_t)node * 2 + 1] = e1 * inv;
        }
    } else {
        constexpr int PER = (DOUT + 3) / 4;
        #pragma unroll
        for (int jj = 0; jj < PER; ++jj) {
            int j = q * PER + jj;
            if (j < DOUT)
                out[(size_t)node * DOUT + j] =
                    fmaxf(af[j] + oinit[(size_t)node * DOUT + j], 0.f);
        }
    }
}

// ---------------------------------------------------------------------------

extern "C" void kernel_launch(void* const* d_in, const int* in_sizes, int n_in,
                              void* d_out, int out_size, void* d_ws, size_t ws_size,
                              hipStream_t stream) {
    const float* x  = (const float*)d_in[0];
    const int*   ei = (const int*)d_in[1];
    const float* ew = (const float*)d_in[2];
    const float* wrel[5]  = { (const float*)d_in[3], (const float*)d_in[6],
                              (const float*)d_in[9], (const float*)d_in[12],
                              (const float*)d_in[15] };
    const float* brel[5]  = { (const float*)d_in[4], (const float*)d_in[7],
                              (const float*)d_in[10], (const float*)d_in[13],
                              (const float*)d_in[16] };
    const float* wroot[5] = { (const float*)d_in[5], (const float*)d_in[8],
                              (const float*)d_in[11], (const float*)d_in[14],
                              (const float*)d_in[17] };

    char* ws = (char*)d_ws;
    size_t off = 0;
    auto alloc = [&](size_t bytes) -> void* {
        void* ptr = ws + off;
        off += (bytes + 255) & ~(size_t)255;
        return ptr;
    };
    // region A: rec1 during sort; reused for p/oinit during layers (rec1 dead then)
    char*  regionA   = (char*)alloc((size_t)N_EDGES * 8);          // 25.6 MB
    uint2* rec1      = (uint2*)regionA;
    float* pbuf      = (float*)regionA;                            // ≤ 6.4 MB
    float* oinit     = (float*)(regionA + (size_t)8 * 1024 * 1024);// ≤ 6.0 MB
    uint2* rec2      = (uint2*)alloc((size_t)N_EDGES * 8);         // 25.6 MB
    float* xpad      = (float*)alloc((size_t)N_NODES * 8 * 4);     // 3.2 MB
    float* fA        = (float*)alloc((size_t)N_NODES * 20 * 4);    // 8.0 MB
    float* fB        = (float*)alloc((size_t)N_NODES * 15 * 4);    // 6.0 MB
    int*   hist_g    = (int*)alloc((size_t)NCHUNK * NB * 4);       // 1.6 MB
    int*   off_g     = (int*)alloc((size_t)NCHUNK * NB * 4);       // 1.6 MB
    int*   tot       = (int*)alloc((size_t)NB * 4);
    int*   bstart    = (int*)alloc((size_t)NB * 4);
    int*   row_start = (int*)alloc((size_t)N_NODES * 4);           // 0.4 MB
    int*   cntb      = (int*)alloc((size_t)N_NODES * 4);           // 0.4 MB

    const int* srcv = ei;            // edge_index row 0
    const int* dstv = ei + N_EDGES;  // edge_index row 1

    const int gN  = (N_NODES + BLOCK - 1) / BLOCK;          // 391
    const int gN4 = (4 * N_NODES + BLOCK - 1) / BLOCK;      // 1563

    pad_x_kernel    <<<gN, BLOCK, 0, stream>>>(x, xpad);
    hist_kernel     <<<NCHUNK, BLOCK, 0, stream>>>(dstv, hist_g);
    chunkscan_kernel<<<(NB + 3) / 4, BLOCK, 0, stream>>>(hist_g, off_g, tot);
    scan_kernel     <<<1, SCAN_T, 0, stream>>>(tot, bstart);
    scatter1_kernel <<<NCHUNK, BLOCK, 0, stream>>>(srcv, dstv, ew, bstart, off_g, rec1);
    scatter2_kernel <<<NB, BLOCK, 0, stream>>>(rec1, bstart, tot, rec2, row_start, cntb);

    // L0: 6 -> 20, aggregate pre-transform
    layer0_kernel<<<gN4, BLOCK, 0, stream>>>(xpad, rec2, row_start, cntb,
                                             wrel[0], brel[0], wroot[0], fA);
    // L1: 20 -> 15
    dense_kernel<20, 15, 16><<<gN, BLOCK, 0, stream>>>(fA, wrel[1], brel[1], wroot[1], pbuf, oinit);
    gather_kernel<15, 16, false><<<gN4, BLOCK, 0, stream>>>(pbuf, oinit, rec2, row_start, cntb, fB);
    // L2: 15 -> 10
    dense_kernel<15, 10, 12><<<gN, BLOCK, 0, stream>>>(fB, wrel[2], brel[2], wroot[2], pbuf, oinit);
    gather_kernel<10, 12, false><<<gN4, BLOCK, 0, stream>>>(pbuf, oinit, rec2, row_start, cntb, fA);
    // L3: 10 -> 5
    dense_kernel<10, 5, 8><<<gN, BLOCK, 0, stream>>>(fA, wrel[3], brel[3], wroot[3], pbuf, oinit);
    gather_kernel<5, 8, false><<<gN4, BLOCK, 0, stream>>>(pbuf, oinit, rec2, row_start, cntb, fB);
    // L4: 5 -> 2, softmax
    dense_kernel<5, 2, 4><<<gN, BLOCK, 0, stream>>>(fB, wrel[4], brel[4], wroot[4], pbuf, oinit);
    gather_kernel<2, 4, true><<<gN4, BLOCK, 0, stream>>>(pbuf, oinit, rec2, row_start, cntb, (float*)d_out);
}

// Round 4
// 457.535 us; speedup vs baseline: 3.6349x; 1.0811x over previous
//
#include <hip/hip_runtime.h>
#include <stdint.h>

#define N_NODES 100000
#define N_EDGES 3200000
#define BN      64                    // nodes per dst-bucket
#define NB      1563                  // ceil(N_NODES / BN)
#define NCHUNK  1024                  // edge chunks (one block each)
#define CH      (N_EDGES / NCHUNK)    // 3125 edges per chunk (exact)
#define CPL     (NCHUNK / 64)         // 16 chunks per lane in chunkscan
#define BLOCK   256

// XCD swizzle: block bid -> chunk c so that each contiguous 128-chunk range
// (a contiguous slice of every bucket's output region, ~3.2 MB) is processed
// on ONE XCD (bid%8 round-robin heuristic) -> its L2 write-combines the
// short (chunk,bucket) runs instead of cross-XCD partial-line writebacks.
__device__ __forceinline__ int chunk_of_block(int bid) {
    return ((bid & 7) << 7) | (bid >> 3);
}

// ---------------------------------------------------------------------------
// Stage 0: pad x (stride 6 -> 8, zero pads) for float4 gathers in layer 0
// ---------------------------------------------------------------------------
__global__ void pad_x_kernel(const float* __restrict__ x, float* __restrict__ xpad) {
    int i = blockIdx.x * blockDim.x + threadIdx.x;
    if (i < N_NODES) {
        const float* xr = x + (size_t)i * 6;
        float4 a, b;
        a.x = xr[0]; a.y = xr[1]; a.z = xr[2]; a.w = xr[3];
        b.x = xr[4]; b.y = xr[5]; b.z = 0.f; b.w = 0.f;
        float4* o = (float4*)(xpad + (size_t)i * 8);
        o[0] = a; o[1] = b;
    }
}

// ---------------------------------------------------------------------------
// Stage 1: per-chunk bucket histogram (LDS-staged, exclusive coalesced rows)
// ---------------------------------------------------------------------------
__global__ void hist_kernel(const int* __restrict__ dst, int* __restrict__ hist_g) {
    __shared__ int h[NB];
    for (int b = threadIdx.x; b < NB; b += BLOCK) h[b] = 0;
    __syncthreads();
    const int c  = blockIdx.x;
    const int k0 = c * CH;
    for (int k = threadIdx.x; k < CH; k += BLOCK)
        atomicAdd(&h[dst[k0 + k] >> 6], 1);
    __syncthreads();
    for (int b = threadIdx.x; b < NB; b += BLOCK)
        hist_g[c * NB + b] = h[b];
}

// ---------------------------------------------------------------------------
// Stage 2a: per-bucket exclusive scan over the 1024 chunk counts (1 wave/bucket)
// ---------------------------------------------------------------------------
__global__ void chunkscan_kernel(const int* __restrict__ hist_g,
                                 int* __restrict__ off_g, int* __restrict__ tot) {
    int w    = (blockIdx.x * blockDim.x + threadIdx.x) >> 6;  // global wave = bucket
    int lane = threadIdx.x & 63;
    if (w >= NB) return;
    int v[CPL];
    int ls = 0;
    const int cbase = lane * CPL;
    #pragma unroll
    for (int i = 0; i < CPL; ++i) { v[i] = hist_g[(cbase + i) * NB + w]; ls += v[i]; }
    int run = ls;
    #pragma unroll
    for (int d = 1; d < 64; d <<= 1) {
        int u = __shfl_up(run, d);
        if (lane >= d) run += u;
    }
    int acc = run - ls;   // exclusive over lanes
    #pragma unroll
    for (int i = 0; i < CPL; ++i) { off_g[(cbase + i) * NB + w] = acc; acc += v[i]; }
    if (lane == 63) tot[w] = acc;
}

// ---------------------------------------------------------------------------
// Stage 2b: exclusive scan of 1563 bucket totals (one wg, 2-level)
// ---------------------------------------------------------------------------
#define SCAN_T   1024
#define SCAN_PER 2
__global__ void scan_kernel(const int* __restrict__ cnt, int* __restrict__ bstart) {
    __shared__ int part[SCAN_T];
    int t = threadIdx.x;
    int local[SCAN_PER];
    int s = 0;
    #pragma unroll
    for (int i = 0; i < SCAN_PER; ++i) {
        int idx = t * SCAN_PER + i;
        int v = (idx < NB) ? cnt[idx] : 0;
        local[i] = s;
        s += v;
    }
    part[t] = s;
    __syncthreads();
    for (int off = 1; off < SCAN_T; off <<= 1) {
        int v = (t >= off) ? part[t - off] : 0;
        __syncthreads();
        part[t] += v;
        __syncthreads();
    }
    int excl = part[t] - s;
    #pragma unroll
    for (int i = 0; i < SCAN_PER; ++i) {
        int idx = t * SCAN_PER + i;
        if (idx < NB) bstart[idx] = excl + local[i];
    }
}

// ---------------------------------------------------------------------------
// Stage 3: scatter pass 1 — bucket-partition edges. Zero global atomics;
// every (chunk,bucket) run is exclusively owned by this block; XCD swizzle
// keeps adjacent runs on one XCD's L2 for write combining.
// rec.x = src (17b) | dst_local (6b) << 17 ; rec.y = weight bits.
// ---------------------------------------------------------------------------
__global__ void scatter1_kernel(const int* __restrict__ src, const int* __restrict__ dst,
                                const float* __restrict__ w,
                                const int* __restrict__ bstart, const int* __restrict__ off_g,
                                uint2* __restrict__ rec1) {
    __shared__ int cur[NB];
    const int c = chunk_of_block(blockIdx.x);
    for (int b = threadIdx.x; b < NB; b += BLOCK)
        cur[b] = bstart[b] + off_g[c * NB + b];
    __syncthreads();
    const int k0 = c * CH;
    for (int k = threadIdx.x; k < CH; k += BLOCK) {
        int e = k0 + k;
        int d = dst[e];
        int b = d >> 6;
        int pos = atomicAdd(&cur[b], 1);   // LDS atomic only
        uint2 r;
        r.x = (uint32_t)src[e] | ((uint32_t)(d & 63) << 17);
        r.y = __float_as_uint(w[e]);
        rec1[pos] = r;
    }
}

// ---------------------------------------------------------------------------
// Stage 4: scatter pass 2 — sort each ~2048-record bucket to node granularity.
// One block per bucket; output range exclusively owned; emits row_start/cnt.
// ---------------------------------------------------------------------------
__global__ void scatter2_kernel(const uint2* __restrict__ rec1,
                                const int* __restrict__ bstart, const int* __restrict__ tot,
                                uint2* __restrict__ rec2,
                                int* __restrict__ row_start, int* __restrict__ cnt) {
    __shared__ int h[BN];
    __shared__ int cur[BN];
    const int b  = blockIdx.x;
    const int s0 = bstart[b];
    const int n  = tot[b];
    if (threadIdx.x < BN) h[threadIdx.x] = 0;
    __syncthreads();
    for (int k = threadIdx.x; k < n; k += BLOCK)
        atomicAdd(&h[rec1[s0 + k].x >> 17], 1);
    __syncthreads();
    if (threadIdx.x < BN) {   // wave 0: exclusive scan of 64 bins
        int v = h[threadIdx.x];
        int run = v;
        #pragma unroll
        for (int d = 1; d < 64; d <<= 1) {
            int u = __shfl_up(run, d);
            if (threadIdx.x >= d) run += u;
        }
        int excl = run - v;
        cur[threadIdx.x] = excl;
        int node = b * BN + threadIdx.x;
        if (node < N_NODES) { row_start[node] = s0 + excl; cnt[node] = v; }
    }
    __syncthreads();
    for (int k = threadIdx.x; k < n; k += BLOCK) {
        uint2 r = rec1[s0 + k];
        int dl = (int)(r.x >> 17);
        int pos = s0 + atomicAdd(&cur[dl], 1);
        rec2[pos] = r;
    }
}

// ---------------------------------------------------------------------------
// Layer 0 (din=6 < dout=20: aggregate pre-transform). 8 lanes per node;
// each lane takes every 8th edge; butterfly shfl-reduce over the 8-lane group;
// lanes split the 20 outputs (3 each, bounds-checked).
// ---------------------------------------------------------------------------
__global__ void layer0_kernel(const float* __restrict__ xpad,
                              const uint2* __restrict__ rec,
                              const int* __restrict__ row_start, const int* __restrict__ cnt,
                              const float* __restrict__ wrel, const float* __restrict__ brel,
                              const float* __restrict__ wroot,
                              float* __restrict__ out) {
    __shared__ float s_wrel[6 * 20];
    __shared__ float s_wroot[6 * 20];
    __shared__ float s_b[20];
    for (int t = threadIdx.x; t < 120; t += BLOCK) {
        s_wrel[t]  = wrel[t];
        s_wroot[t] = wroot[t];
    }
    if (threadIdx.x < 20) s_b[threadIdx.x] = brel[threadIdx.x];
    __syncthreads();

    int t = blockIdx.x * blockDim.x + threadIdx.x;
    int node = t >> 3;
    int q    = t & 7;
    if (node >= N_NODES) return;

    float4 a0 = make_float4(0.f, 0.f, 0.f, 0.f);
    float4 a1 = make_float4(0.f, 0.f, 0.f, 0.f);
    const int s = row_start[node];
    const int e = s + cnt[node];
    for (int k = s + q; k < e; k += 8) {
        uint2 r = rec[k];
        float w = __uint_as_float(r.y);
        const float4* xs = (const float4*)(xpad + (size_t)(r.x & 0x1FFFF) * 8);
        float4 x0 = xs[0], x1 = xs[1];
        a0.x += w * x0.x; a0.y += w * x0.y; a0.z += w * x0.z; a0.w += w * x0.w;
        a1.x += w * x1.x; a1.y += w * x1.y;
    }
    float agg[6] = { a0.x, a0.y, a0.z, a0.w, a1.x, a1.y };
    #pragma unroll
    for (int i = 0; i < 6; ++i) {
        agg[i] += __shfl_xor(agg[i], 1);
        agg[i] += __shfl_xor(agg[i], 2);
        agg[i] += __shfl_xor(agg[i], 4);
    }
    const float4* xsf = (const float4*)(xpad + (size_t)node * 8);
    float4 x0 = xsf[0], x1 = xsf[1];
    float xv[6] = { x0.x, x0.y, x0.z, x0.w, x1.x, x1.y };

    const int j0 = q * 3;
    #pragma unroll
    for (int jj = 0; jj < 3; ++jj) {
        int j = j0 + jj;
        if (j < 20) {
            float o = s_b[j];
            #pragma unroll
            for (int i = 0; i < 6; ++i)
                o += agg[i] * s_wrel[i * 20 + j] + xv[i] * s_wroot[i * 20 + j];
            out[(size_t)node * 20 + j] = fmaxf(o, 0.f);
        }
    }
}

// ---------------------------------------------------------------------------
// Layers 1..4: dense pre-kernel (node-parallel):
//   p     = x @ Wrel          [N, SP]  (padded, pads = 0; gathered later)
//   oinit = x @ Wroot + b     [N, DOUT]
// ---------------------------------------------------------------------------
template<int DIN, int DOUT, int SP>
__global__ void dense_kernel(const float* __restrict__ xin,
                             const float* __restrict__ wrel, const float* __restrict__ brel,
                             const float* __restrict__ wroot,
                             float* __restrict__ p, float* __restrict__ oinit) {
    __shared__ float s_wrel[DIN * DOUT];
    __shared__ float s_wroot[DIN * DOUT];
    __shared__ float s_b[DOUT];
    for (int t = threadIdx.x; t < DIN * DOUT; t += BLOCK) {
        s_wrel[t]  = wrel[t];
        s_wroot[t] = wroot[t];
    }
    if (threadIdx.x < DOUT) s_b[threadIdx.x] = brel[threadIdx.x];
    __syncthreads();

    int node = blockIdx.x * blockDim.x + threadIdx.x;
    if (node >= N_NODES) return;

    float xv[DIN];
    #pragma unroll
    for (int i = 0; i < DIN; ++i) xv[i] = xin[(size_t)node * DIN + i];

    float pv[DOUT], ov[DOUT];
    #pragma unroll
    for (int j = 0; j < DOUT; ++j) { pv[j] = 0.f; ov[j] = s_b[j]; }
    #pragma unroll
    for (int i = 0; i < DIN; ++i) {
        float xi = xv[i];
        #pragma unroll
        for (int j = 0; j < DOUT; ++j) {
            pv[j] += xi * s_wrel[i * DOUT + j];
            ov[j] += xi * s_wroot[i * DOUT + j];
        }
    }
    #pragma unroll
    for (int j = 0; j < DOUT; ++j) {
        p[(size_t)node * SP + j]       = pv[j];
        oinit[(size_t)node * DOUT + j] = ov[j];
    }
    #pragma unroll
    for (int j = DOUT; j < SP; ++j) p[(size_t)node * SP + j] = 0.f;
}

// ---------------------------------------------------------------------------
// Layers 1..4: gather kernel (post-transform aggregation in DOUT dim).
// 8 lanes/node, butterfly reduce, lanes split outputs. LAST fuses softmax.
// ---------------------------------------------------------------------------
template<int DOUT, int SP, bool LAST>
__global__ void gather_kernel(const float* __restrict__ p, const float* __restrict__ oinit,
                              const uint2* __restrict__ rec,
                              const int* __restrict__ row_start, const int* __restrict__ cnt,
                              float* __restrict__ out) {
    int t = blockIdx.x * blockDim.x + threadIdx.x;
    int node = t >> 3;
    int q    = t & 7;
    if (node >= N_NODES) return;

    constexpr int NV = SP / 4;
    float4 acc[NV];
    #pragma unroll
    for (int v = 0; v < NV; ++v) acc[v] = make_float4(0.f, 0.f, 0.f, 0.f);

    const int s = row_start[node];
    const int e = s + cnt[node];
    for (int k = s + q; k < e; k += 8) {
        uint2 r = rec[k];
        float w = __uint_as_float(r.y);
        const float4* ps = (const float4*)(p + (size_t)(r.x & 0x1FFFF) * SP);
        #pragma unroll
        for (int v = 0; v < NV; ++v) {
            float4 pv = ps[v];
            acc[v].x += w * pv.x;
            acc[v].y += w * pv.y;
            acc[v].z += w * pv.z;
            acc[v].w += w * pv.w;
        }
    }
    float* af = (float*)acc;
    #pragma unroll
    for (int i = 0; i < SP; ++i) {
        af[i] += __shfl_xor(af[i], 1);
        af[i] += __shfl_xor(af[i], 2);
        af[i] += __shfl_xor(af[i], 4);
    }

    if (LAST) {
        if (q == 0) {
            float o0 = af[0] + oinit[(size_t)node * 2 + 0];
            float o1 = af[1] + oinit[(size_t)node * 2 + 1];
            float m = fmaxf(o0, o1);
            float e0 = __expf(o0 - m), e1 = __expf(o1 - m);
            float inv = 1.f / (e0 + e1);
            out[(size_t)node * 2 + 0] = e0 * inv;
            out[(size_t)node * 2 + 1] = e1 * inv;
        }
    } else {
        constexpr int PER = (DOUT + 7) / 8;
        #pragma unroll
        for (int jj = 0; jj < PER; ++jj) {
            int j = q * PER + jj;
            if (j < DOUT)
                out[(size_t)node * DOUT + j] =
                    fmaxf(af[j] + oinit[(size_t)node * DOUT + j], 0.f);
        }
    }
}

// ---------------------------------------------------------------------------

extern "C" void kernel_launch(void* const* d_in, const int* in_sizes, int n_in,
                              void* d_out, int out_size, void* d_ws, size_t ws_size,
                              hipStream_t stream) {
    const float* x  = (const float*)d_in[0];
    const int*   ei = (const int*)d_in[1];
    const float* ew = (const float*)d_in[2];
    const float* wrel[5]  = { (const float*)d_in[3], (const float*)d_in[6],
                              (const float*)d_in[9], (const float*)d_in[12],
                              (const float*)d_in[15] };
    const float* brel[5]  = { (const float*)d_in[4], (const float*)d_in[7],
                              (const float*)d_in[10], (const float*)d_in[13],
                              (const float*)d_in[16] };
    const float* wroot[5] = { (const float*)d_in[5], (const float*)d_in[8],
                              (const float*)d_in[11], (const float*)d_in[14],
                              (const float*)d_in[17] };

    char* ws = (char*)d_ws;
    size_t off = 0;
    auto alloc = [&](size_t bytes) -> void* {
        void* ptr = ws + off;
        off += (bytes + 255) & ~(size_t)255;
        return ptr;
    };
    // region A: rec1 during sort; reused for p/oinit during layers (rec1 dead then)
    char*  regionA   = (char*)alloc((size_t)N_EDGES * 8);          // 25.6 MB
    uint2* rec1      = (uint2*)regionA;
    float* pbuf      = (float*)regionA;                            // ≤ 6.4 MB
    float* oinit     = (float*)(regionA + (size_t)8 * 1024 * 1024);// ≤ 6.0 MB
    uint2* rec2      = (uint2*)alloc((size_t)N_EDGES * 8);         // 25.6 MB
    float* xpad      = (float*)alloc((size_t)N_NODES * 8 * 4);     // 3.2 MB
    // region B: hist_g+off_g during sort (12.8 MB); fA+fB during layers (14 MB)
    char*  regionB   = (char*)alloc((size_t)14 * 1024 * 1024);
    int*   hist_g    = (int*)regionB;                              // 6.4 MB
    int*   off_g     = (int*)(regionB + (size_t)NCHUNK * NB * 4);  // 6.4 MB
    float* fA        = (float*)regionB;                            // 8.0 MB
    float* fB        = (float*)(regionB + (size_t)8 * 1024 * 1024);// 6.0 MB
    int*   tot       = (int*)alloc((size_t)NB * 4);
    int*   bstart    = (int*)alloc((size_t)NB * 4);
    int*   row_start = (int*)alloc((size_t)N_NODES * 4);           // 0.4 MB
    int*   cntb      = (int*)alloc((size_t)N_NODES * 4);           // 0.4 MB

    const int* srcv = ei;            // edge_index row 0
    const int* dstv = ei + N_EDGES;  // edge_index row 1

    const int gN  = (N_NODES + BLOCK - 1) / BLOCK;          // 391
    const int gN8 = (8 * N_NODES + BLOCK - 1) / BLOCK;      // 3125

    pad_x_kernel    <<<gN, BLOCK, 0, stream>>>(x, xpad);
    hist_kernel     <<<NCHUNK, BLOCK, 0, stream>>>(dstv, hist_g);
    chunkscan_kernel<<<(NB + 3) / 4, BLOCK, 0, stream>>>(hist_g, off_g, tot);
    scan_kernel     <<<1, SCAN_T, 0, stream>>>(tot, bstart);
    scatter1_kernel <<<NCHUNK, BLOCK, 0, stream>>>(srcv, dstv, ew, bstart, off_g, rec1);
    scatter2_kernel <<<NB, BLOCK, 0, stream>>>(rec1, bstart, tot, rec2, row_start, cntb);

    // L0: 6 -> 20, aggregate pre-transform
    layer0_kernel<<<gN8, BLOCK, 0, stream>>>(xpad, rec2, row_start, cntb,
                                             wrel[0], brel[0], wroot[0], fA);
    // L1: 20 -> 15
    dense_kernel<20, 15, 16><<<gN, BLOCK, 0, stream>>>(fA, wrel[1], brel[1], wroot[1], pbuf, oinit);
    gather_kernel<15, 16, false><<<gN8, BLOCK, 0, stream>>>(pbuf, oinit, rec2, row_start, cntb, fB);
    // L2: 15 -> 10
    dense_kernel<15, 10, 12><<<gN, BLOCK, 0, stream>>>(fB, wrel[2], brel[2], wroot[2], pbuf, oinit);
    gather_kernel<10, 12, false><<<gN8, BLOCK, 0, stream>>>(pbuf, oinit, rec2, row_start, cntb, fA);
    // L3: 10 -> 5
    dense_kernel<10, 5, 8><<<gN, BLOCK, 0, stream>>>(fA, wrel[3], brel[3], wroot[3], pbuf, oinit);
    gather_kernel<5, 8, false><<<gN8, BLOCK, 0, stream>>>(pbuf, oinit, rec2, row_start, cntb, fB);
    // L4: 5 -> 2, softmax
    dense_kernel<5, 2, 4><<<gN, BLOCK, 0, stream>>>(fB, wrel[4], brel[4], wroot[4], pbuf, oinit);
    gather_kernel<2, 4, true><<<gN8, BLOCK, 0, stream>>>(pbuf, oinit, rec2, row_start, cntb, (float*)d_out);
}

// Round 5
// 383.427 us; speedup vs baseline: 4.3375x; 1.1933x over previous
//
#include <hip/hip_runtime.h>
#include <hip/hip_fp16.h>
#include <stdint.h>

#define N_NODES 100000
#define N_EDGES 3200000
#define BN      64                    // nodes per dst-bucket
#define NB      1563                  // ceil(N_NODES / BN)
#define NCHUNK  1024                  // edge chunks (one block each)
#define CH      (N_EDGES / NCHUNK)    // 3125 edges per chunk (exact)
#define CPL     (NCHUNK / 64)         // 16 chunks per lane in chunkscan
#define BLOCK   256

// XCD swizzle: block bid -> chunk c so each contiguous 128-chunk range is
// processed on one XCD (bid%8 heuristic) -> L2 write-combines short runs.
__device__ __forceinline__ int chunk_of_block(int bid) {
    return ((bid & 7) << 7) | (bid >> 3);
}

// ---------------------------------------------------------------------------
// Stage 0: x (fp32, 6/node) -> xpad (fp16, 8 halves = 16 B/node, pads zero)
// ---------------------------------------------------------------------------
__global__ void pad_x_kernel(const float* __restrict__ x, __half* __restrict__ xpad) {
    int i = blockIdx.x * blockDim.x + threadIdx.x;
    if (i < N_NODES) {
        const float* xr = x + (size_t)i * 6;
        __half2 h[4];
        h[0] = __halves2half2(__float2half(xr[0]), __float2half(xr[1]));
        h[1] = __halves2half2(__float2half(xr[2]), __float2half(xr[3]));
        h[2] = __halves2half2(__float2half(xr[4]), __float2half(xr[5]));
        h[3] = __halves2half2(__float2half(0.f),   __float2half(0.f));
        *(uint4*)(xpad + (size_t)i * 8) = *(uint4*)h;
    }
}

// ---------------------------------------------------------------------------
// Stage 1: per-chunk bucket histogram (LDS-staged, exclusive coalesced rows)
// ---------------------------------------------------------------------------
__global__ void hist_kernel(const int* __restrict__ dst, int* __restrict__ hist_g) {
    __shared__ int h[NB];
    for (int b = threadIdx.x; b < NB; b += BLOCK) h[b] = 0;
    __syncthreads();
    const int c  = blockIdx.x;
    const int k0 = c * CH;
    for (int k = threadIdx.x; k < CH; k += BLOCK)
        atomicAdd(&h[dst[k0 + k] >> 6], 1);
    __syncthreads();
    for (int b = threadIdx.x; b < NB; b += BLOCK)
        hist_g[c * NB + b] = h[b];
}

// ---------------------------------------------------------------------------
// Stage 2a: per-bucket exclusive scan over the 1024 chunk counts (1 wave/bucket)
// ---------------------------------------------------------------------------
__global__ void chunkscan_kernel(const int* __restrict__ hist_g,
                                 int* __restrict__ off_g, int* __restrict__ tot) {
    int w    = (blockIdx.x * blockDim.x + threadIdx.x) >> 6;
    int lane = threadIdx.x & 63;
    if (w >= NB) return;
    int v[CPL];
    int ls = 0;
    const int cbase = lane * CPL;
    #pragma unroll
    for (int i = 0; i < CPL; ++i) { v[i] = hist_g[(cbase + i) * NB + w]; ls += v[i]; }
    int run = ls;
    #pragma unroll
    for (int d = 1; d < 64; d <<= 1) {
        int u = __shfl_up(run, d);
        if (lane >= d) run += u;
    }
    int acc = run - ls;
    #pragma unroll
    for (int i = 0; i < CPL; ++i) { off_g[(cbase + i) * NB + w] = acc; acc += v[i]; }
    if (lane == 63) tot[w] = acc;
}

// ---------------------------------------------------------------------------
// Stage 2b: exclusive scan of 1563 bucket totals (one wg, 2-level)
// ---------------------------------------------------------------------------
#define SCAN_T   1024
#define SCAN_PER 2
__global__ void scan_kernel(const int* __restrict__ cnt, int* __restrict__ bstart) {
    __shared__ int part[SCAN_T];
    int t = threadIdx.x;
    int local[SCAN_PER];
    int s = 0;
    #pragma unroll
    for (int i = 0; i < SCAN_PER; ++i) {
        int idx = t * SCAN_PER + i;
        int v = (idx < NB) ? cnt[idx] : 0;
        local[i] = s;
        s += v;
    }
    part[t] = s;
    __syncthreads();
    for (int off = 1; off < SCAN_T; off <<= 1) {
        int v = (t >= off) ? part[t - off] : 0;
        __syncthreads();
        part[t] += v;
        __syncthreads();
    }
    int excl = part[t] - s;
    #pragma unroll
    for (int i = 0; i < SCAN_PER; ++i) {
        int idx = t * SCAN_PER + i;
        if (idx < NB) bstart[idx] = excl + local[i];
    }
}

// ---------------------------------------------------------------------------
// Stage 3: scatter pass 1 — bucket-partition edges; LDS cursors only.
// rec.x = src (17b) | dst_local (6b) << 17 ; rec.y = weight bits.
// ---------------------------------------------------------------------------
__global__ void scatter1_kernel(const int* __restrict__ src, const int* __restrict__ dst,
                                const float* __restrict__ w,
                                const int* __restrict__ bstart, const int* __restrict__ off_g,
                                uint2* __restrict__ rec1) {
    __shared__ int cur[NB];
    const int c = chunk_of_block(blockIdx.x);
    for (int b = threadIdx.x; b < NB; b += BLOCK)
        cur[b] = bstart[b] + off_g[c * NB + b];
    __syncthreads();
    const int k0 = c * CH;
    for (int k = threadIdx.x; k < CH; k += BLOCK) {
        int e = k0 + k;
        int d = dst[e];
        int b = d >> 6;
        int pos = atomicAdd(&cur[b], 1);
        uint2 r;
        r.x = (uint32_t)src[e] | ((uint32_t)(d & 63) << 17);
        r.y = __float_as_uint(w[e]);
        rec1[pos] = r;
    }
}

// ---------------------------------------------------------------------------
// Stage 4: scatter pass 2 — sort each ~2048-record bucket to node granularity.
// ---------------------------------------------------------------------------
__global__ void scatter2_kernel(const uint2* __restrict__ rec1,
                                const int* __restrict__ bstart, const int* __restrict__ tot,
                                uint2* __restrict__ rec2,
                                int* __restrict__ row_start, int* __restrict__ cnt) {
    __shared__ int h[BN];
    __shared__ int cur[BN];
    const int b  = blockIdx.x;
    const int s0 = bstart[b];
    const int n  = tot[b];
    if (threadIdx.x < BN) h[threadIdx.x] = 0;
    __syncthreads();
    for (int k = threadIdx.x; k < n; k += BLOCK)
        atomicAdd(&h[rec1[s0 + k].x >> 17], 1);
    __syncthreads();
    if (threadIdx.x < BN) {
        int v = h[threadIdx.x];
        int run = v;
        #pragma unroll
        for (int d = 1; d < 64; d <<= 1) {
            int u = __shfl_up(run, d);
            if (threadIdx.x >= d) run += u;
        }
        int excl = run - v;
        cur[threadIdx.x] = excl;
        int node = b * BN + threadIdx.x;
        if (node < N_NODES) { row_start[node] = s0 + excl; cnt[node] = v; }
    }
    __syncthreads();
    for (int k = threadIdx.x; k < n; k += BLOCK) {
        uint2 r = rec1[s0 + k];
        int dl = (int)(r.x >> 17);
        int pos = s0 + atomicAdd(&cur[dl], 1);
        rec2[pos] = r;
    }
}

// ---------------------------------------------------------------------------
// Layer 0 (6 -> 20, aggregate pre-transform). 8 lanes/node, fp16 gather
// (one uint4 = 8 halves per edge), fp32 accumulate, butterfly reduce.
// ---------------------------------------------------------------------------
__global__ void layer0_kernel(const __half* __restrict__ xpad,
                              const uint2* __restrict__ rec,
                              const int* __restrict__ row_start, const int* __restrict__ cnt,
                              const float* __restrict__ wrel, const float* __restrict__ brel,
                              const float* __restrict__ wroot,
                              float* __restrict__ out) {
    __shared__ float s_wrel[6 * 20];
    __shared__ float s_wroot[6 * 20];
    __shared__ float s_b[20];
    for (int t = threadIdx.x; t < 120; t += BLOCK) {
        s_wrel[t]  = wrel[t];
        s_wroot[t] = wroot[t];
    }
    if (threadIdx.x < 20) s_b[threadIdx.x] = brel[threadIdx.x];
    __syncthreads();

    int t = blockIdx.x * blockDim.x + threadIdx.x;
    int node = t >> 3;
    int q    = t & 7;
    if (node >= N_NODES) return;

    float agg[6] = {0.f, 0.f, 0.f, 0.f, 0.f, 0.f};
    const int s = row_start[node];
    const int e = s + cnt[node];
    for (int k = s + q; k < e; k += 8) {
        uint2 r = rec[k];
        float w = __uint_as_float(r.y);
        uint4 raw = *(const uint4*)(xpad + (size_t)(r.x & 0x1FFFF) * 8);
        const __half2* h = (const __half2*)&raw;
        agg[0] += w * __low2float(h[0]);  agg[1] += w * __high2float(h[0]);
        agg[2] += w * __low2float(h[1]);  agg[3] += w * __high2float(h[1]);
        agg[4] += w * __low2float(h[2]);  agg[5] += w * __high2float(h[2]);
    }
    #pragma unroll
    for (int i = 0; i < 6; ++i) {
        agg[i] += __shfl_xor(agg[i], 1);
        agg[i] += __shfl_xor(agg[i], 2);
        agg[i] += __shfl_xor(agg[i], 4);
    }
    uint4 raws = *(const uint4*)(xpad + (size_t)node * 8);
    const __half2* hs = (const __half2*)&raws;
    float xv[6] = { __low2float(hs[0]), __high2float(hs[0]),
                    __low2float(hs[1]), __high2float(hs[1]),
                    __low2float(hs[2]), __high2float(hs[2]) };

    const int j0 = q * 3;
    #pragma unroll
    for (int jj = 0; jj < 3; ++jj) {
        int j = j0 + jj;
        if (j < 20) {
            float o = s_b[j];
            #pragma unroll
            for (int i = 0; i < 6; ++i)
                o += agg[i] * s_wrel[i * 20 + j] + xv[i] * s_wroot[i * 20 + j];
            out[(size_t)node * 20 + j] = fmaxf(o, 0.f);
        }
    }
}

// ---------------------------------------------------------------------------
// Layers 1..4: dense pre-kernel (node-parallel):
//   p     = x @ Wrel   [N, SPH] fp16, pads zero (gathered later)
//   oinit = x @ Wroot + b  [N, DOUT] fp32
// ---------------------------------------------------------------------------
template<int DIN, int DOUT, int SPH>
__global__ void dense_kernel(const float* __restrict__ xin,
                             const float* __restrict__ wrel, const float* __restrict__ brel,
                             const float* __restrict__ wroot,
                             __half* __restrict__ p, float* __restrict__ oinit) {
    __shared__ float s_wrel[DIN * DOUT];
    __shared__ float s_wroot[DIN * DOUT];
    __shared__ float s_b[DOUT];
    for (int t = threadIdx.x; t < DIN * DOUT; t += BLOCK) {
        s_wrel[t]  = wrel[t];
        s_wroot[t] = wroot[t];
    }
    if (threadIdx.x < DOUT) s_b[threadIdx.x] = brel[threadIdx.x];
    __syncthreads();

    int node = blockIdx.x * blockDim.x + threadIdx.x;
    if (node >= N_NODES) return;

    float xv[DIN];
    #pragma unroll
    for (int i = 0; i < DIN; ++i) xv[i] = xin[(size_t)node * DIN + i];

    float pv[DOUT], ov[DOUT];
    #pragma unroll
    for (int j = 0; j < DOUT; ++j) { pv[j] = 0.f; ov[j] = s_b[j]; }
    #pragma unroll
    for (int i = 0; i < DIN; ++i) {
        float xi = xv[i];
        #pragma unroll
        for (int j = 0; j < DOUT; ++j) {
            pv[j] += xi * s_wrel[i * DOUT + j];
            ov[j] += xi * s_wroot[i * DOUT + j];
        }
    }
    __half2* prow = (__half2*)(p + (size_t)node * SPH);
    #pragma unroll
    for (int jj = 0; jj < SPH / 2; ++jj) {
        float a = (2 * jj     < DOUT) ? pv[2 * jj]     : 0.f;
        float b = (2 * jj + 1 < DOUT) ? pv[2 * jj + 1] : 0.f;
        prow[jj] = __halves2half2(__float2half(a), __float2half(b));
    }
    #pragma unroll
    for (int j = 0; j < DOUT; ++j) oinit[(size_t)node * DOUT + j] = ov[j];
}

// ---------------------------------------------------------------------------
// Layers 1..4: gather kernel. 8 lanes/node; fp16 p rows (SPH halves),
// fp32 accumulate, butterfly reduce; LAST fuses softmax.
// ---------------------------------------------------------------------------
template<int DOUT, int SPH, bool LAST>
__global__ void gather_kernel(const __half* __restrict__ p, const float* __restrict__ oinit,
                              const uint2* __restrict__ rec,
                              const int* __restrict__ row_start, const int* __restrict__ cnt,
                              float* __restrict__ out) {
    int t = blockIdx.x * blockDim.x + threadIdx.x;
    int node = t >> 3;
    int q    = t & 7;
    if (node >= N_NODES) return;

    float af[SPH];
    #pragma unroll
    for (int i = 0; i < SPH; ++i) af[i] = 0.f;

    const int s = row_start[node];
    const int e = s + cnt[node];
    for (int k = s + q; k < e; k += 8) {
        uint2 r = rec[k];
        float w = __uint_as_float(r.y);
        const __half* ps = p + (size_t)(r.x & 0x1FFFF) * SPH;
        if constexpr (SPH >= 8) {
            #pragma unroll
            for (int v = 0; v < SPH / 8; ++v) {
                uint4 raw = ((const uint4*)ps)[v];
                const __half2* h = (const __half2*)&raw;
                #pragma unroll
                for (int jj = 0; jj < 4; ++jj) {
                    af[v * 8 + 2 * jj]     += w * __low2float(h[jj]);
                    af[v * 8 + 2 * jj + 1] += w * __high2float(h[jj]);
                }
            }
        } else {  // SPH == 2
            uint32_t raw = *(const uint32_t*)ps;
            __half2 h = *(const __half2*)&raw;
            af[0] += w * __low2float(h);
            af[1] += w * __high2float(h);
        }
    }
    #pragma unroll
    for (int i = 0; i < SPH; ++i) {
        af[i] += __shfl_xor(af[i], 1);
        af[i] += __shfl_xor(af[i], 2);
        af[i] += __shfl_xor(af[i], 4);
    }

    if (LAST) {
        if (q == 0) {
            float o0 = af[0] + oinit[(size_t)node * 2 + 0];
            float o1 = af[1] + oinit[(size_t)node * 2 + 1];
            float m = fmaxf(o0, o1);
            float e0 = __expf(o0 - m), e1 = __expf(o1 - m);
            float inv = 1.f / (e0 + e1);
            out[(size_t)node * 2 + 0] = e0 * inv;
            out[(size_t)node * 2 + 1] = e1 * inv;
        }
    } else {
        constexpr int PER = (DOUT + 7) / 8;
        #pragma unroll
        for (int jj = 0; jj < PER; ++jj) {
            int j = q * PER + jj;
            if (j < DOUT)
                out[(size_t)node * DOUT + j] =
                    fmaxf(af[j] + oinit[(size_t)node * DOUT + j], 0.f);
        }
    }
}

// ---------------------------------------------------------------------------

extern "C" void kernel_launch(void* const* d_in, const int* in_sizes, int n_in,
                              void* d_out, int out_size, void* d_ws, size_t ws_size,
                              hipStream_t stream) {
    const float* x  = (const float*)d_in[0];
    const int*   ei = (const int*)d_in[1];
    const float* ew = (const float*)d_in[2];
    const float* wrel[5]  = { (const float*)d_in[3], (const float*)d_in[6],
                              (const float*)d_in[9], (const float*)d_in[12],
                              (const float*)d_in[15] };
    const float* brel[5]  = { (const float*)d_in[4], (const float*)d_in[7],
                              (const float*)d_in[10], (const float*)d_in[13],
                              (const float*)d_in[16] };
    const float* wroot[5] = { (const float*)d_in[5], (const float*)d_in[8],
                              (const float*)d_in[11], (const float*)d_in[14],
                              (const float*)d_in[17] };

    char* ws = (char*)d_ws;
    size_t off = 0;
    auto alloc = [&](size_t bytes) -> void* {
        void* ptr = ws + off;
        off += (bytes + 255) & ~(size_t)255;
        return ptr;
    };
    // region A: rec1 during sort; reused for p/oinit during layers (rec1 dead then)
    char*   regionA   = (char*)alloc((size_t)N_EDGES * 8);          // 25.6 MB
    uint2*  rec1      = (uint2*)regionA;
    __half* pbuf      = (__half*)regionA;                           // ≤ 3.2 MB (fp16)
    float*  oinit     = (float*)(regionA + (size_t)8 * 1024 * 1024);// ≤ 6.0 MB
    uint2*  rec2      = (uint2*)alloc((size_t)N_EDGES * 8);         // 25.6 MB
    __half* xpad      = (__half*)alloc((size_t)N_NODES * 8 * 2);    // 1.6 MB
    // region B: hist_g+off_g during sort (12.8 MB); fA+fB during layers (14 MB)
    char*   regionB   = (char*)alloc((size_t)14 * 1024 * 1024);
    int*    hist_g    = (int*)regionB;                              // 6.4 MB
    int*    off_g     = (int*)(regionB + (size_t)NCHUNK * NB * 4);  // 6.4 MB
    float*  fA        = (float*)regionB;                            // 8.0 MB
    float*  fB        = (float*)(regionB + (size_t)8 * 1024 * 1024);// 6.0 MB
    int*    tot       = (int*)alloc((size_t)NB * 4);
    int*    bstart    = (int*)alloc((size_t)NB * 4);
    int*    row_start = (int*)alloc((size_t)N_NODES * 4);
    int*    cntb      = (int*)alloc((size_t)N_NODES * 4);

    const int* srcv = ei;            // edge_index row 0
    const int* dstv = ei + N_EDGES;  // edge_index row 1

    const int gN  = (N_NODES + BLOCK - 1) / BLOCK;          // 391
    const int gN8 = (8 * N_NODES + BLOCK - 1) / BLOCK;      // 3125

    pad_x_kernel    <<<gN, BLOCK, 0, stream>>>(x, xpad);
    hist_kernel     <<<NCHUNK, BLOCK, 0, stream>>>(dstv, hist_g);
    chunkscan_kernel<<<(NB + 3) / 4, BLOCK, 0, stream>>>(hist_g, off_g, tot);
    scan_kernel     <<<1, SCAN_T, 0, stream>>>(tot, bstart);
    scatter1_kernel <<<NCHUNK, BLOCK, 0, stream>>>(srcv, dstv, ew, bstart, off_g, rec1);
    scatter2_kernel <<<NB, BLOCK, 0, stream>>>(rec1, bstart, tot, rec2, row_start, cntb);

    // L0: 6 -> 20, aggregate pre-transform (fp16 gather of xpad)
    layer0_kernel<<<gN8, BLOCK, 0, stream>>>(xpad, rec2, row_start, cntb,
                                             wrel[0], brel[0], wroot[0], fA);
    // L1: 20 -> 15  (p: 16 halves = 32 B/node, 3.2 MB)
    dense_kernel<20, 15, 16><<<gN, BLOCK, 0, stream>>>(fA, wrel[1], brel[1], wroot[1], pbuf, oinit);
    gather_kernel<15, 16, false><<<gN8, BLOCK, 0, stream>>>(pbuf, oinit, rec2, row_start, cntb, fB);
    // L2: 15 -> 10  (p: 16 halves, 3.2 MB)
    dense_kernel<15, 10, 16><<<gN, BLOCK, 0, stream>>>(fB, wrel[2], brel[2], wroot[2], pbuf, oinit);
    gather_kernel<10, 16, false><<<gN8, BLOCK, 0, stream>>>(pbuf, oinit, rec2, row_start, cntb, fA);
    // L3: 10 -> 5   (p: 8 halves = 16 B/node, 1.6 MB)
    dense_kernel<10, 5, 8><<<gN, BLOCK, 0, stream>>>(fA, wrel[3], brel[3], wroot[3], pbuf, oinit);
    gather_kernel<5, 8, false><<<gN8, BLOCK, 0, stream>>>(pbuf, oinit, rec2, row_start, cntb, fB);
    // L4: 5 -> 2, softmax  (p: 2 halves = 4 B/node, 0.4 MB)
    dense_kernel<5, 2, 2><<<gN, BLOCK, 0, stream>>>(fB, wrel[4], brel[4], wroot[4], pbuf, oinit);
    gather_kernel<2, 2, true><<<gN8, BLOCK, 0, stream>>>(pbuf, oinit, rec2, row_start, cntb, (float*)d_out);
}

// Round 6
// 357.754 us; speedup vs baseline: 4.6488x; 1.0718x over previous
//
#include <hip/hip_runtime.h>
#include <hip/hip_fp16.h>
#include <stdint.h>

#define N_NODES 100000
#define N_EDGES 3200000
#define BN      64                    // nodes per dst-bucket
#define NB      1563                  // ceil(N_NODES / BN)
// histogram granularity (fine, for occupancy)
#define NCH_H   1024
#define CH_H    (N_EDGES / NCH_H)     // 3125
#define CPL     (NCH_H / 64)          // 16 chunks per lane in chunkscan
// scatter granularity (coarse, for long runs)
#define NCH_S   256
#define CH_S    (N_EDGES / NCH_S)     // 12500
#define BS1     512                   // scatter1 block size
#define S1_IT   ((CH_S + BS1 - 1) / BS1)   // 25 dst values cached per thread
#define S2_CAP  2560                  // scatter2 LDS stage capacity
#define BLOCK   256

// ---------------------------------------------------------------------------
// Stage 0: x (fp32, 6/node) -> xpad (fp16, 8 halves = 16 B/node, pads zero)
// ---------------------------------------------------------------------------
__global__ void pad_x_kernel(const float* __restrict__ x, __half* __restrict__ xpad) {
    int i = blockIdx.x * blockDim.x + threadIdx.x;
    if (i < N_NODES) {
        const float* xr = x + (size_t)i * 6;
        __half2 h[4];
        h[0] = __halves2half2(__float2half(xr[0]), __float2half(xr[1]));
        h[1] = __halves2half2(__float2half(xr[2]), __float2half(xr[3]));
        h[2] = __halves2half2(__float2half(xr[4]), __float2half(xr[5]));
        h[3] = __halves2half2(__float2half(0.f),   __float2half(0.f));
        *(uint4*)(xpad + (size_t)i * 8) = *(uint4*)h;
    }
}

// ---------------------------------------------------------------------------
// Stage 1: per-subchunk bucket histogram (1024 subchunks of 3125)
// ---------------------------------------------------------------------------
__global__ void hist_kernel(const int* __restrict__ dst, int* __restrict__ hist_g) {
    __shared__ int h[NB];
    for (int b = threadIdx.x; b < NB; b += BLOCK) h[b] = 0;
    __syncthreads();
    const int c  = blockIdx.x;
    const int k0 = c * CH_H;
    for (int k = threadIdx.x; k < CH_H; k += BLOCK)
        atomicAdd(&h[dst[k0 + k] >> 6], 1);
    __syncthreads();
    for (int b = threadIdx.x; b < NB; b += BLOCK)
        hist_g[c * NB + b] = h[b];
}

// ---------------------------------------------------------------------------
// Stage 2a: per-bucket exclusive scan over the 1024 subchunk counts
// ---------------------------------------------------------------------------
__global__ void chunkscan_kernel(const int* __restrict__ hist_g,
                                 int* __restrict__ off_g, int* __restrict__ tot) {
    int w    = (blockIdx.x * blockDim.x + threadIdx.x) >> 6;
    int lane = threadIdx.x & 63;
    if (w >= NB) return;
    int v[CPL];
    int ls = 0;
    const int cbase = lane * CPL;
    #pragma unroll
    for (int i = 0; i < CPL; ++i) { v[i] = hist_g[(cbase + i) * NB + w]; ls += v[i]; }
    int run = ls;
    #pragma unroll
    for (int d = 1; d < 64; d <<= 1) {
        int u = __shfl_up(run, d);
        if (lane >= d) run += u;
    }
    int acc = run - ls;
    #pragma unroll
    for (int i = 0; i < CPL; ++i) { off_g[(cbase + i) * NB + w] = acc; acc += v[i]; }
    if (lane == 63) tot[w] = acc;
}

// ---------------------------------------------------------------------------
// Stage 2b: exclusive scan of 1563 bucket totals (one wg)
// ---------------------------------------------------------------------------
#define SCAN_T   1024
#define SCAN_PER 2
__global__ void scan_kernel(const int* __restrict__ cnt, int* __restrict__ bstart) {
    __shared__ int part[SCAN_T];
    int t = threadIdx.x;
    int local[SCAN_PER];
    int s = 0;
    #pragma unroll
    for (int i = 0; i < SCAN_PER; ++i) {
        int idx = t * SCAN_PER + i;
        int v = (idx < NB) ? cnt[idx] : 0;
        local[i] = s;
        s += v;
    }
    part[t] = s;
    __syncthreads();
    for (int off = 1; off < SCAN_T; off <<= 1) {
        int v = (t >= off) ? part[t - off] : 0;
        __syncthreads();
        part[t] += v;
        __syncthreads();
    }
    int excl = part[t] - s;
    #pragma unroll
    for (int i = 0; i < SCAN_PER; ++i) {
        int idx = t * SCAN_PER + i;
        if (idx < NB) bstart[idx] = excl + local[i];
    }
}

// ---------------------------------------------------------------------------
// Stage 3: scatter pass 1, stage-and-flush. One block per 12500-edge chunk.
// LDS stage holds packed tokens (le:14 | dl:6 | b:11); flush walks the stage
// in order so lane-contiguous stores emit full 64 B lines (runs avg 8 recs).
// rec1 record: x = src(17) | dl(6)<<17 ; y = weight bits.
// ---------------------------------------------------------------------------
__global__ void __launch_bounds__(BS1)
scatter1_kernel(const int* __restrict__ src, const int* __restrict__ dst,
                const float* __restrict__ w,
                const int* __restrict__ bstart, const int* __restrict__ off_g,
                uint2* __restrict__ rec1) {
    __shared__ uint32_t stage[CH_S];   // 50000 B
    __shared__ int h[NB];              // hist -> cursor
    __shared__ int delta[NB];          // global_base - local_start
    __shared__ int wtot[BS1 / 64];

    const int c  = blockIdx.x;
    const int k0 = c * CH_S;
    const int t  = threadIdx.x;

    // phase 1: histogram (cache dst in regs)
    for (int b = t; b < NB; b += BS1) h[b] = 0;
    __syncthreads();
    int dstv[S1_IT];
    int nit = 0;
    for (int k = t; k < CH_S; k += BS1, ++nit) {
        int d = dst[k0 + k];
        dstv[nit] = d;
        atomicAdd(&h[d >> 6], 1);
    }
    __syncthreads();

    // phase 2: block scan of h -> cursor start (in h) + delta
    {
        const int base = t * 4;          // 512*4 = 2048 >= NB
        int v[4], ls = 0;
        #pragma unroll
        for (int i = 0; i < 4; ++i) {
            int idx = base + i;
            v[i] = (idx < NB) ? h[idx] : 0;
            ls += v[i];
        }
        int lane = t & 63, wv = t >> 6;
        int run = ls;
        #pragma unroll
        for (int d = 1; d < 64; d <<= 1) {
            int u = __shfl_up(run, d);
            if (lane >= d) run += u;
        }
        if (lane == 63) wtot[wv] = run;
        __syncthreads();
        int wexcl = 0;
        for (int i = 0; i < wv; ++i) wexcl += wtot[i];
        int excl = wexcl + run - ls;
        #pragma unroll
        for (int i = 0; i < 4; ++i) {
            int idx = base + i;
            if (idx < NB) {
                int gb = bstart[idx] + off_g[(size_t)(4 * c) * NB + idx];
                h[idx]     = excl;        // cursor
                delta[idx] = gb - excl;   // flush addr = delta[b] + stage_idx
                excl += v[i];
            }
        }
    }
    __syncthreads();

    // phase 3: scatter packed tokens into stage (LDS cursors)
    nit = 0;
    for (int k = t; k < CH_S; k += BS1, ++nit) {
        int d = dstv[nit];
        int b = d >> 6;
        int pos = atomicAdd(&h[b], 1);
        stage[pos] = (uint32_t)k | ((uint32_t)(d & 63) << 14) | ((uint32_t)b << 20);
    }
    __syncthreads();

    // phase 4: flush in stage order -> lane-contiguous full-line stores
    for (int i = t; i < CH_S; i += BS1) {
        uint32_t sv = stage[i];
        int le = sv & 0x3FFF;
        int dl = (sv >> 14) & 0x3F;
        int b  = sv >> 20;
        int e  = k0 + le;
        uint2 r;
        r.x = (uint32_t)src[e] | ((uint32_t)dl << 17);
        r.y = __float_as_uint(w[e]);
        rec1[delta[b] + i] = r;
    }
}

// ---------------------------------------------------------------------------
// Stage 4: scatter pass 2 — node-sort each bucket through an LDS stage,
// flush fully coalesced. One block per bucket.
// ---------------------------------------------------------------------------
__global__ void scatter2_kernel(const uint2* __restrict__ rec1,
                                const int* __restrict__ bstart, const int* __restrict__ tot,
                                uint2* __restrict__ rec2,
                                int* __restrict__ row_start, int* __restrict__ cnt) {
    __shared__ int h[BN];
    __shared__ int cur[BN];
    __shared__ uint2 stage[S2_CAP];
    const int b  = blockIdx.x;
    const int s0 = bstart[b];
    const int n  = tot[b];
    if (threadIdx.x < BN) h[threadIdx.x] = 0;
    __syncthreads();
    for (int k = threadIdx.x; k < n; k += BLOCK)
        atomicAdd(&h[rec1[s0 + k].x >> 17], 1);
    __syncthreads();
    if (threadIdx.x < BN) {
        int v = h[threadIdx.x];
        int run = v;
        #pragma unroll
        for (int d = 1; d < 64; d <<= 1) {
            int u = __shfl_up(run, d);
            if (threadIdx.x >= d) run += u;
        }
        int excl = run - v;
        cur[threadIdx.x] = excl;
        int node = b * BN + threadIdx.x;
        if (node < N_NODES) { row_start[node] = s0 + excl; cnt[node] = v; }
    }
    __syncthreads();
    for (int k = threadIdx.x; k < n; k += BLOCK) {
        uint2 r = rec1[s0 + k];
        int dl = (int)(r.x >> 17);
        int pos = atomicAdd(&cur[dl], 1);
        if (pos < S2_CAP) stage[pos] = r;
        else              rec2[s0 + pos] = r;   // overflow fallback (p ~ 0)
    }
    __syncthreads();
    for (int i = threadIdx.x; i < n && i < S2_CAP; i += BLOCK)
        rec2[s0 + i] = stage[i];                // coalesced full-line flush
}

// ---------------------------------------------------------------------------
// Layer 0 (6 -> 20, aggregate pre-transform). 8 lanes/node, fp16 gather,
// fp32 accumulate, butterfly reduce.
// ---------------------------------------------------------------------------
__global__ void layer0_kernel(const __half* __restrict__ xpad,
                              const uint2* __restrict__ rec,
                              const int* __restrict__ row_start, const int* __restrict__ cnt,
                              const float* __restrict__ wrel, const float* __restrict__ brel,
                              const float* __restrict__ wroot,
                              float* __restrict__ out) {
    __shared__ float s_wrel[6 * 20];
    __shared__ float s_wroot[6 * 20];
    __shared__ float s_b[20];
    for (int t = threadIdx.x; t < 120; t += BLOCK) {
        s_wrel[t]  = wrel[t];
        s_wroot[t] = wroot[t];
    }
    if (threadIdx.x < 20) s_b[threadIdx.x] = brel[threadIdx.x];
    __syncthreads();

    int t = blockIdx.x * blockDim.x + threadIdx.x;
    int node = t >> 3;
    int q    = t & 7;
    if (node >= N_NODES) return;

    float agg[6] = {0.f, 0.f, 0.f, 0.f, 0.f, 0.f};
    const int s = row_start[node];
    const int e = s + cnt[node];
    for (int k = s + q; k < e; k += 8) {
        uint2 r = rec[k];
        float w = __uint_as_float(r.y);
        uint4 raw = *(const uint4*)(xpad + (size_t)(r.x & 0x1FFFF) * 8);
        const __half2* h = (const __half2*)&raw;
        agg[0] += w * __low2float(h[0]);  agg[1] += w * __high2float(h[0]);
        agg[2] += w * __low2float(h[1]);  agg[3] += w * __high2float(h[1]);
        agg[4] += w * __low2float(h[2]);  agg[5] += w * __high2float(h[2]);
    }
    #pragma unroll
    for (int i = 0; i < 6; ++i) {
        agg[i] += __shfl_xor(agg[i], 1);
        agg[i] += __shfl_xor(agg[i], 2);
        agg[i] += __shfl_xor(agg[i], 4);
    }
    uint4 raws = *(const uint4*)(xpad + (size_t)node * 8);
    const __half2* hs = (const __half2*)&raws;
    float xv[6] = { __low2float(hs[0]), __high2float(hs[0]),
                    __low2float(hs[1]), __high2float(hs[1]),
                    __low2float(hs[2]), __high2float(hs[2]) };

    const int j0 = q * 3;
    #pragma unroll
    for (int jj = 0; jj < 3; ++jj) {
        int j = j0 + jj;
        if (j < 20) {
            float o = s_b[j];
            #pragma unroll
            for (int i = 0; i < 6; ++i)
                o += agg[i] * s_wrel[i * 20 + j] + xv[i] * s_wroot[i * 20 + j];
            out[(size_t)node * 20 + j] = fmaxf(o, 0.f);
        }
    }
}

// ---------------------------------------------------------------------------
// Layers 1..4: dense pre-kernel:  p = x@Wrel (fp16, padded), oinit = x@Wroot+b
// ---------------------------------------------------------------------------
template<int DIN, int DOUT, int SPH>
__global__ void dense_kernel(const float* __restrict__ xin,
                             const float* __restrict__ wrel, const float* __restrict__ brel,
                             const float* __restrict__ wroot,
                             __half* __restrict__ p, float* __restrict__ oinit) {
    __shared__ float s_wrel[DIN * DOUT];
    __shared__ float s_wroot[DIN * DOUT];
    __shared__ float s_b[DOUT];
    for (int t = threadIdx.x; t < DIN * DOUT; t += BLOCK) {
        s_wrel[t]  = wrel[t];
        s_wroot[t] = wroot[t];
    }
    if (threadIdx.x < DOUT) s_b[threadIdx.x] = brel[threadIdx.x];
    __syncthreads();

    int node = blockIdx.x * blockDim.x + threadIdx.x;
    if (node >= N_NODES) return;

    float xv[DIN];
    #pragma unroll
    for (int i = 0; i < DIN; ++i) xv[i] = xin[(size_t)node * DIN + i];

    float pv[DOUT], ov[DOUT];
    #pragma unroll
    for (int j = 0; j < DOUT; ++j) { pv[j] = 0.f; ov[j] = s_b[j]; }
    #pragma unroll
    for (int i = 0; i < DIN; ++i) {
        float xi = xv[i];
        #pragma unroll
        for (int j = 0; j < DOUT; ++j) {
            pv[j] += xi * s_wrel[i * DOUT + j];
            ov[j] += xi * s_wroot[i * DOUT + j];
        }
    }
    __half2* prow = (__half2*)(p + (size_t)node * SPH);
    #pragma unroll
    for (int jj = 0; jj < SPH / 2; ++jj) {
        float a = (2 * jj     < DOUT) ? pv[2 * jj]     : 0.f;
        float b = (2 * jj + 1 < DOUT) ? pv[2 * jj + 1] : 0.f;
        prow[jj] = __halves2half2(__float2half(a), __float2half(b));
    }
    #pragma unroll
    for (int j = 0; j < DOUT; ++j) oinit[(size_t)node * DOUT + j] = ov[j];
}

// ---------------------------------------------------------------------------
// Layers 1..4: gather kernel. 8 lanes/node; fp16 p rows, fp32 accumulate.
// ---------------------------------------------------------------------------
template<int DOUT, int SPH, bool LAST>
__global__ void gather_kernel(const __half* __restrict__ p, const float* __restrict__ oinit,
                              const uint2* __restrict__ rec,
                              const int* __restrict__ row_start, const int* __restrict__ cnt,
                              float* __restrict__ out) {
    int t = blockIdx.x * blockDim.x + threadIdx.x;
    int node = t >> 3;
    int q    = t & 7;
    if (node >= N_NODES) return;

    float af[SPH];
    #pragma unroll
    for (int i = 0; i < SPH; ++i) af[i] = 0.f;

    const int s = row_start[node];
    const int e = s + cnt[node];
    for (int k = s + q; k < e; k += 8) {
        uint2 r = rec[k];
        float w = __uint_as_float(r.y);
        const __half* ps = p + (size_t)(r.x & 0x1FFFF) * SPH;
        if constexpr (SPH >= 8) {
            #pragma unroll
            for (int v = 0; v < SPH / 8; ++v) {
                uint4 raw = ((const uint4*)ps)[v];
                const __half2* h = (const __half2*)&raw;
                #pragma unroll
                for (int jj = 0; jj < 4; ++jj) {
                    af[v * 8 + 2 * jj]     += w * __low2float(h[jj]);
                    af[v * 8 + 2 * jj + 1] += w * __high2float(h[jj]);
                }
            }
        } else {
            uint32_t raw = *(const uint32_t*)ps;
            __half2 h = *(const __half2*)&raw;
            af[0] += w * __low2float(h);
            af[1] += w * __high2float(h);
        }
    }
    #pragma unroll
    for (int i = 0; i < SPH; ++i) {
        af[i] += __shfl_xor(af[i], 1);
        af[i] += __shfl_xor(af[i], 2);
        af[i] += __shfl_xor(af[i], 4);
    }

    if (LAST) {
        if (q == 0) {
            float o0 = af[0] + oinit[(size_t)node * 2 + 0];
            float o1 = af[1] + oinit[(size_t)node * 2 + 1];
            float m = fmaxf(o0, o1);
            float e0 = __expf(o0 - m), e1 = __expf(o1 - m);
            float inv = 1.f / (e0 + e1);
            out[(size_t)node * 2 + 0] = e0 * inv;
            out[(size_t)node * 2 + 1] = e1 * inv;
        }
    } else {
        constexpr int PER = (DOUT + 7) / 8;
        #pragma unroll
        for (int jj = 0; jj < PER; ++jj) {
            int j = q * PER + jj;
            if (j < DOUT)
                out[(size_t)node * DOUT + j] =
                    fmaxf(af[j] + oinit[(size_t)node * DOUT + j], 0.f);
        }
    }
}

// ---------------------------------------------------------------------------

extern "C" void kernel_launch(void* const* d_in, const int* in_sizes, int n_in,
                              void* d_out, int out_size, void* d_ws, size_t ws_size,
                              hipStream_t stream) {
    const float* x  = (const float*)d_in[0];
    const int*   ei = (const int*)d_in[1];
    const float* ew = (const float*)d_in[2];
    const float* wrel[5]  = { (const float*)d_in[3], (const float*)d_in[6],
                              (const float*)d_in[9], (const float*)d_in[12],
                              (const float*)d_in[15] };
    const float* brel[5]  = { (const float*)d_in[4], (const float*)d_in[7],
                              (const float*)d_in[10], (const float*)d_in[13],
                              (const float*)d_in[16] };
    const float* wroot[5] = { (const float*)d_in[5], (const float*)d_in[8],
                              (const float*)d_in[11], (const float*)d_in[14],
                              (const float*)d_in[17] };

    char* ws = (char*)d_ws;
    size_t off = 0;
    auto alloc = [&](size_t bytes) -> void* {
        void* ptr = ws + off;
        off += (bytes + 255) & ~(size_t)255;
        return ptr;
    };
    // region A: rec1 during sort; reused for p/oinit during layers
    char*   regionA   = (char*)alloc((size_t)N_EDGES * 8);          // 25.6 MB
    uint2*  rec1      = (uint2*)regionA;
    __half* pbuf      = (__half*)regionA;                           // ≤ 3.2 MB
    float*  oinit     = (float*)(regionA + (size_t)8 * 1024 * 1024);// ≤ 6.0 MB
    uint2*  rec2      = (uint2*)alloc((size_t)N_EDGES * 8);         // 25.6 MB
    __half* xpad      = (__half*)alloc((size_t)N_NODES * 8 * 2);    // 1.6 MB
    // region B: hist_g+off_g during sort; fA+fB during layers
    char*   regionB   = (char*)alloc((size_t)14 * 1024 * 1024);
    int*    hist_g    = (int*)regionB;                              // 6.4 MB
    int*    off_g     = (int*)(regionB + (size_t)NCH_H * NB * 4);   // 6.4 MB
    float*  fA        = (float*)regionB;                            // 8.0 MB
    float*  fB        = (float*)(regionB + (size_t)8 * 1024 * 1024);// 6.0 MB
    int*    tot       = (int*)alloc((size_t)NB * 4);
    int*    bstart    = (int*)alloc((size_t)NB * 4);
    int*    row_start = (int*)alloc((size_t)N_NODES * 4);
    int*    cntb      = (int*)alloc((size_t)N_NODES * 4);

    const int* srcv = ei;            // edge_index row 0
    const int* dstv = ei + N_EDGES;  // edge_index row 1

    const int gN  = (N_NODES + BLOCK - 1) / BLOCK;          // 391
    const int gN8 = (8 * N_NODES + BLOCK - 1) / BLOCK;      // 3125

    pad_x_kernel    <<<gN, BLOCK, 0, stream>>>(x, xpad);
    hist_kernel     <<<NCH_H, BLOCK, 0, stream>>>(dstv, hist_g);
    chunkscan_kernel<<<(NB + 3) / 4, BLOCK, 0, stream>>>(hist_g, off_g, tot);
    scan_kernel     <<<1, SCAN_T, 0, stream>>>(tot, bstart);
    scatter1_kernel <<<NCH_S, BS1, 0, stream>>>(srcv, dstv, ew, bstart, off_g, rec1);
    scatter2_kernel <<<NB, BLOCK, 0, stream>>>(rec1, bstart, tot, rec2, row_start, cntb);

    // L0: 6 -> 20, aggregate pre-transform (fp16 gather of xpad)
    layer0_kernel<<<gN8, BLOCK, 0, stream>>>(xpad, rec2, row_start, cntb,
                                             wrel[0], brel[0], wroot[0], fA);
    // L1: 20 -> 15
    dense_kernel<20, 15, 16><<<gN, BLOCK, 0, stream>>>(fA, wrel[1], brel[1], wroot[1], pbuf, oinit);
    gather_kernel<15, 16, false><<<gN8, BLOCK, 0, stream>>>(pbuf, oinit, rec2, row_start, cntb, fB);
    // L2: 15 -> 10
    dense_kernel<15, 10, 16><<<gN, BLOCK, 0, stream>>>(fB, wrel[2], brel[2], wroot[2], pbuf, oinit);
    gather_kernel<10, 16, false><<<gN8, BLOCK, 0, stream>>>(pbuf, oinit, rec2, row_start, cntb, fA);
    // L3: 10 -> 5
    dense_kernel<10, 5, 8><<<gN, BLOCK, 0, stream>>>(fA, wrel[3], brel[3], wroot[3], pbuf, oinit);
    gather_kernel<5, 8, false><<<gN8, BLOCK, 0, stream>>>(pbuf, oinit, rec2, row_start, cntb, fB);
    // L4: 5 -> 2, softmax
    dense_kernel<5, 2, 2><<<gN, BLOCK, 0, stream>>>(fB, wrel[4], brel[4], wroot[4], pbuf, oinit);
    gather_kernel<2, 2, true><<<gN8, BLOCK, 0, stream>>>(pbuf, oinit, rec2, row_start, cntb, (float*)d_out);
}

// Round 7
// 343.011 us; speedup vs baseline: 4.8486x; 1.0430x over previous
//
#include <hip/hip_runtime.h>
#include <hip/hip_fp16.h>
#include <stdint.h>

#define N_NODES 100000
#define N_EDGES 3200000
#define BN      64                    // nodes per dst-bucket
#define NB      1563                  // ceil(N_NODES / BN)
// histogram granularity (fine)
#define NCH_H   1024
#define CH_H    (N_EDGES / NCH_H)     // 3125
#define CPL     (NCH_H / 64)          // 16 chunks per lane in chunkscan
// scatter granularity (coarse, for long coalesced runs)
#define NCH_S   256
#define CH_S    (N_EDGES / NCH_S)     // 12500
#define BS1     1024                  // scatter1 block size (16 waves/CU)
#define S1_IT   ((CH_S + BS1 - 1) / BS1)   // 13 dst values cached per thread
#define S2_CAP  2560                  // scatter2 LDS stage capacity
#define BLOCK   256
#define W_SCALE 32767.0f
#define W_INV   (1.0f / 32767.0f)

// ---------------------------------------------------------------------------
// Stage 0: x (fp32, 6/node) -> xpad (fp16, 8 halves = 16 B/node, pads zero)
// ---------------------------------------------------------------------------
__global__ void pad_x_kernel(const float* __restrict__ x, __half* __restrict__ xpad) {
    int i = blockIdx.x * blockDim.x + threadIdx.x;
    if (i < N_NODES) {
        const float* xr = x + (size_t)i * 6;
        __half2 h[4];
        h[0] = __halves2half2(__float2half(xr[0]), __float2half(xr[1]));
        h[1] = __halves2half2(__float2half(xr[2]), __float2half(xr[3]));
        h[2] = __halves2half2(__float2half(xr[4]), __float2half(xr[5]));
        h[3] = __halves2half2(__float2half(0.f),   __float2half(0.f));
        *(uint4*)(xpad + (size_t)i * 8) = *(uint4*)h;
    }
}

// ---------------------------------------------------------------------------
// Stage 1: per-subchunk bucket histogram (1024 subchunks of 3125)
// ---------------------------------------------------------------------------
__global__ void hist_kernel(const int* __restrict__ dst, int* __restrict__ hist_g) {
    __shared__ int h[NB];
    for (int b = threadIdx.x; b < NB; b += BLOCK) h[b] = 0;
    __syncthreads();
    const int c  = blockIdx.x;
    const int k0 = c * CH_H;
    for (int k = threadIdx.x; k < CH_H; k += BLOCK)
        atomicAdd(&h[dst[k0 + k] >> 6], 1);
    __syncthreads();
    for (int b = threadIdx.x; b < NB; b += BLOCK)
        hist_g[c * NB + b] = h[b];
}

// ---------------------------------------------------------------------------
// Stage 2a: per-bucket exclusive scan over the 1024 subchunk counts
// ---------------------------------------------------------------------------
__global__ void chunkscan_kernel(const int* __restrict__ hist_g,
                                 int* __restrict__ off_g, int* __restrict__ tot) {
    int w    = (blockIdx.x * blockDim.x + threadIdx.x) >> 6;
    int lane = threadIdx.x & 63;
    if (w >= NB) return;
    int v[CPL];
    int ls = 0;
    const int cbase = lane * CPL;
    #pragma unroll
    for (int i = 0; i < CPL; ++i) { v[i] = hist_g[(cbase + i) * NB + w]; ls += v[i]; }
    int run = ls;
    #pragma unroll
    for (int d = 1; d < 64; d <<= 1) {
        int u = __shfl_up(run, d);
        if (lane >= d) run += u;
    }
    int acc = run - ls;
    #pragma unroll
    for (int i = 0; i < CPL; ++i) { off_g[(cbase + i) * NB + w] = acc; acc += v[i]; }
    if (lane == 63) tot[w] = acc;
}

// ---------------------------------------------------------------------------
// Stage 2b: exclusive scan of 1563 bucket totals (one wg)
// ---------------------------------------------------------------------------
#define SCAN_T   1024
#define SCAN_PER 2
__global__ void scan_kernel(const int* __restrict__ cnt, int* __restrict__ bstart) {
    __shared__ int part[SCAN_T];
    int t = threadIdx.x;
    int local[SCAN_PER];
    int s = 0;
    #pragma unroll
    for (int i = 0; i < SCAN_PER; ++i) {
        int idx = t * SCAN_PER + i;
        int v = (idx < NB) ? cnt[idx] : 0;
        local[i] = s;
        s += v;
    }
    part[t] = s;
    __syncthreads();
    for (int off = 1; off < SCAN_T; off <<= 1) {
        int v = (t >= off) ? part[t - off] : 0;
        __syncthreads();
        part[t] += v;
        __syncthreads();
    }
    int excl = part[t] - s;
    #pragma unroll
    for (int i = 0; i < SCAN_PER; ++i) {
        int idx = t * SCAN_PER + i;
        if (idx < NB) bstart[idx] = excl + local[i];
    }
}

// ---------------------------------------------------------------------------
// Stage 3: scatter pass 1, stage-and-flush. One 1024-thread block per
// 12500-edge chunk (16 waves/CU). Flush in stage order -> full-line stores.
// rec1 record: x = src(17) | dl(6)<<17 ; y = weight fp32 bits.
// ---------------------------------------------------------------------------
__global__ void __launch_bounds__(BS1)
scatter1_kernel(const int* __restrict__ src, const int* __restrict__ dst,
                const float* __restrict__ w,
                const int* __restrict__ bstart, const int* __restrict__ off_g,
                uint2* __restrict__ rec1) {
    __shared__ uint32_t stage[CH_S];   // 50000 B
    __shared__ int h[NB];              // hist -> cursor
    __shared__ int delta[NB];          // global_base - local_start
    __shared__ int wtot[BS1 / 64];

    const int c  = blockIdx.x;
    const int k0 = c * CH_S;
    const int t  = threadIdx.x;

    // phase 1: histogram (cache dst in regs)
    for (int b = t; b < NB; b += BS1) h[b] = 0;
    __syncthreads();
    int dstv[S1_IT];
    int nit = 0;
    for (int k = t; k < CH_S; k += BS1, ++nit) {
        int d = dst[k0 + k];
        dstv[nit] = d;
        atomicAdd(&h[d >> 6], 1);
    }
    __syncthreads();

    // phase 2: block scan of h -> cursor start (in h) + delta
    {
        const int base = t * 2;          // 1024*2 = 2048 >= NB
        int v[2], ls = 0;
        #pragma unroll
        for (int i = 0; i < 2; ++i) {
            int idx = base + i;
            v[i] = (idx < NB) ? h[idx] : 0;
            ls += v[i];
        }
        int lane = t & 63, wv = t >> 6;
        int run = ls;
        #pragma unroll
        for (int d = 1; d < 64; d <<= 1) {
            int u = __shfl_up(run, d);
            if (lane >= d) run += u;
        }
        if (lane == 63) wtot[wv] = run;
        __syncthreads();
        int wexcl = 0;
        for (int i = 0; i < wv; ++i) wexcl += wtot[i];
        int excl = wexcl + run - ls;
        #pragma unroll
        for (int i = 0; i < 2; ++i) {
            int idx = base + i;
            if (idx < NB) {
                int gb = bstart[idx] + off_g[(size_t)(4 * c) * NB + idx];
                h[idx]     = excl;        // cursor (stage offset)
                delta[idx] = gb - excl;   // flush addr = delta[b] + stage_idx
                excl += v[i];
            }
        }
    }
    __syncthreads();

    // phase 3: scatter packed tokens into stage (LDS cursors)
    // token = le(14) | dl(6)<<14 | b(11)<<20
    nit = 0;
    for (int k = t; k < CH_S; k += BS1, ++nit) {
        int d = dstv[nit];
        int b = d >> 6;
        int pos = atomicAdd(&h[b], 1);
        stage[pos] = (uint32_t)k | ((uint32_t)(d & 63) << 14) | ((uint32_t)b << 20);
    }
    __syncthreads();

    // phase 4: flush in stage order -> lane-contiguous full-line stores
    for (int i = t; i < CH_S; i += BS1) {
        uint32_t sv = stage[i];
        int le = sv & 0x3FFF;
        int dl = (sv >> 14) & 0x3F;
        int b  = sv >> 20;
        int e  = k0 + le;
        uint2 r;
        r.x = (uint32_t)src[e] | ((uint32_t)dl << 17);
        r.y = __float_as_uint(w[e]);
        rec1[delta[b] + i] = r;
    }
}

// ---------------------------------------------------------------------------
// Stage 4: scatter pass 2 — node-sort each bucket through an LDS stage.
// Output record shrinks to 4 B: src(17) | w15(15)<<17 (dl no longer needed;
// gathers only use src+w, and w as 15-bit fixed point has abs err 1.5e-5).
// ---------------------------------------------------------------------------
__global__ void scatter2_kernel(const uint2* __restrict__ rec1,
                                const int* __restrict__ bstart, const int* __restrict__ tot,
                                uint32_t* __restrict__ rec2,
                                int* __restrict__ row_start, int* __restrict__ cnt) {
    __shared__ int h[BN];
    __shared__ int cur[BN];
    __shared__ uint32_t stage[S2_CAP];
    const int b  = blockIdx.x;
    const int s0 = bstart[b];
    const int n  = tot[b];
    if (threadIdx.x < BN) h[threadIdx.x] = 0;
    __syncthreads();
    for (int k = threadIdx.x; k < n; k += BLOCK)
        atomicAdd(&h[rec1[s0 + k].x >> 17], 1);
    __syncthreads();
    if (threadIdx.x < BN) {
        int v = h[threadIdx.x];
        int run = v;
        #pragma unroll
        for (int d = 1; d < 64; d <<= 1) {
            int u = __shfl_up(run, d);
            if (threadIdx.x >= d) run += u;
        }
        int excl = run - v;
        cur[threadIdx.x] = excl;
        int node = b * BN + threadIdx.x;
        if (node < N_NODES) { row_start[node] = s0 + excl; cnt[node] = v; }
    }
    __syncthreads();
    for (int k = threadIdx.x; k < n; k += BLOCK) {
        uint2 r = rec1[s0 + k];
        int dl = (int)(r.x >> 17);
        float wv = __uint_as_float(r.y);
        uint32_t w15 = (uint32_t)__float2uint_rn(wv * W_SCALE);
        uint32_t r2 = (r.x & 0x1FFFF) | (w15 << 17);
        int pos = atomicAdd(&cur[dl], 1);
        if (pos < S2_CAP) stage[pos] = r2;
        else              rec2[s0 + pos] = r2;  // overflow fallback (p ~ 0)
    }
    __syncthreads();
    for (int i = threadIdx.x; i < n && i < S2_CAP; i += BLOCK)
        rec2[s0 + i] = stage[i];                // coalesced full-line flush
}

// ---------------------------------------------------------------------------
// Layer 0 (6 -> 20, aggregate pre-transform). 8 lanes/node, fp16 gather,
// fp32 accumulate, butterfly reduce. 4 B edge records.
// ---------------------------------------------------------------------------
__global__ void layer0_kernel(const __half* __restrict__ xpad,
                              const uint32_t* __restrict__ rec,
                              const int* __restrict__ row_start, const int* __restrict__ cnt,
                              const float* __restrict__ wrel, const float* __restrict__ brel,
                              const float* __restrict__ wroot,
                              float* __restrict__ out) {
    __shared__ float s_wrel[6 * 20];
    __shared__ float s_wroot[6 * 20];
    __shared__ float s_b[20];
    for (int t = threadIdx.x; t < 120; t += BLOCK) {
        s_wrel[t]  = wrel[t];
        s_wroot[t] = wroot[t];
    }
    if (threadIdx.x < 20) s_b[threadIdx.x] = brel[threadIdx.x];
    __syncthreads();

    int t = blockIdx.x * blockDim.x + threadIdx.x;
    int node = t >> 3;
    int q    = t & 7;
    if (node >= N_NODES) return;

    float agg[6] = {0.f, 0.f, 0.f, 0.f, 0.f, 0.f};
    const int s = row_start[node];
    const int e = s + cnt[node];
    for (int k = s + q; k < e; k += 8) {
        uint32_t r = rec[k];
        float w = (float)(r >> 17) * W_INV;
        uint4 raw = *(const uint4*)(xpad + (size_t)(r & 0x1FFFF) * 8);
        const __half2* h = (const __half2*)&raw;
        agg[0] += w * __low2float(h[0]);  agg[1] += w * __high2float(h[0]);
        agg[2] += w * __low2float(h[1]);  agg[3] += w * __high2float(h[1]);
        agg[4] += w * __low2float(h[2]);  agg[5] += w * __high2float(h[2]);
    }
    #pragma unroll
    for (int i = 0; i < 6; ++i) {
        agg[i] += __shfl_xor(agg[i], 1);
        agg[i] += __shfl_xor(agg[i], 2);
        agg[i] += __shfl_xor(agg[i], 4);
    }
    uint4 raws = *(const uint4*)(xpad + (size_t)node * 8);
    const __half2* hs = (const __half2*)&raws;
    float xv[6] = { __low2float(hs[0]), __high2float(hs[0]),
                    __low2float(hs[1]), __high2float(hs[1]),
                    __low2float(hs[2]), __high2float(hs[2]) };

    const int j0 = q * 3;
    #pragma unroll
    for (int jj = 0; jj < 3; ++jj) {
        int j = j0 + jj;
        if (j < 20) {
            float o = s_b[j];
            #pragma unroll
            for (int i = 0; i < 6; ++i)
                o += agg[i] * s_wrel[i * 20 + j] + xv[i] * s_wroot[i * 20 + j];
            out[(size_t)node * 20 + j] = fmaxf(o, 0.f);
        }
    }
}

// ---------------------------------------------------------------------------
// Layers 1..4: dense pre-kernel:  p = x@Wrel (fp16, padded), oinit = x@Wroot+b
// ---------------------------------------------------------------------------
template<int DIN, int DOUT, int SPH>
__global__ void dense_kernel(const float* __restrict__ xin,
                             const float* __restrict__ wrel, const float* __restrict__ brel,
                             const float* __restrict__ wroot,
                             __half* __restrict__ p, float* __restrict__ oinit) {
    __shared__ float s_wrel[DIN * DOUT];
    __shared__ float s_wroot[DIN * DOUT];
    __shared__ float s_b[DOUT];
    for (int t = threadIdx.x; t < DIN * DOUT; t += BLOCK) {
        s_wrel[t]  = wrel[t];
        s_wroot[t] = wroot[t];
    }
    if (threadIdx.x < DOUT) s_b[threadIdx.x] = brel[threadIdx.x];
    __syncthreads();

    int node = blockIdx.x * blockDim.x + threadIdx.x;
    if (node >= N_NODES) return;

    float xv[DIN];
    #pragma unroll
    for (int i = 0; i < DIN; ++i) xv[i] = xin[(size_t)node * DIN + i];

    float pv[DOUT], ov[DOUT];
    #pragma unroll
    for (int j = 0; j < DOUT; ++j) { pv[j] = 0.f; ov[j] = s_b[j]; }
    #pragma unroll
    for (int i = 0; i < DIN; ++i) {
        float xi = xv[i];
        #pragma unroll
        for (int j = 0; j < DOUT; ++j) {
            pv[j] += xi * s_wrel[i * DOUT + j];
            ov[j] += xi * s_wroot[i * DOUT + j];
        }
    }
    __half2* prow = (__half2*)(p + (size_t)node * SPH);
    #pragma unroll
    for (int jj = 0; jj < SPH / 2; ++jj) {
        float a = (2 * jj     < DOUT) ? pv[2 * jj]     : 0.f;
        float b = (2 * jj + 1 < DOUT) ? pv[2 * jj + 1] : 0.f;
        prow[jj] = __halves2half2(__float2half(a), __float2half(b));
    }
    #pragma unroll
    for (int j = 0; j < DOUT; ++j) oinit[(size_t)node * DOUT + j] = ov[j];
}

// ---------------------------------------------------------------------------
// Layers 1..4: gather kernel. 8 lanes/node; 4 B edge records; fp16 p rows,
// fp32 accumulate, butterfly reduce; LAST fuses softmax.
// ---------------------------------------------------------------------------
template<int DOUT, int SPH, bool LAST>
__global__ void gather_kernel(const __half* __restrict__ p, const float* __restrict__ oinit,
                              const uint32_t* __restrict__ rec,
                              const int* __restrict__ row_start, const int* __restrict__ cnt,
                              float* __restrict__ out) {
    int t = blockIdx.x * blockDim.x + threadIdx.x;
    int node = t >> 3;
    int q    = t & 7;
    if (node >= N_NODES) return;

    float af[SPH];
    #pragma unroll
    for (int i = 0; i < SPH; ++i) af[i] = 0.f;

    const int s = row_start[node];
    const int e = s + cnt[node];
    for (int k = s + q; k < e; k += 8) {
        uint32_t r = rec[k];
        float w = (float)(r >> 17) * W_INV;
        const __half* ps = p + (size_t)(r & 0x1FFFF) * SPH;
        if constexpr (SPH >= 8) {
            #pragma unroll
            for (int v = 0; v < SPH / 8; ++v) {
                uint4 raw = ((const uint4*)ps)[v];
                const __half2* h = (const __half2*)&raw;
                #pragma unroll
                for (int jj = 0; jj < 4; ++jj) {
                    af[v * 8 + 2 * jj]     += w * __low2float(h[jj]);
                    af[v * 8 + 2 * jj + 1] += w * __high2float(h[jj]);
                }
            }
        } else {
            uint32_t raw = *(const uint32_t*)ps;
            __half2 h = *(const __half2*)&raw;
            af[0] += w * __low2float(h);
            af[1] += w * __high2float(h);
        }
    }
    #pragma unroll
    for (int i = 0; i < SPH; ++i) {
        af[i] += __shfl_xor(af[i], 1);
        af[i] += __shfl_xor(af[i], 2);
        af[i] += __shfl_xor(af[i], 4);
    }

    if (LAST) {
        if (q == 0) {
            float o0 = af[0] + oinit[(size_t)node * 2 + 0];
            float o1 = af[1] + oinit[(size_t)node * 2 + 1];
            float m = fmaxf(o0, o1);
            float e0 = __expf(o0 - m), e1 = __expf(o1 - m);
            float inv = 1.f / (e0 + e1);
            out[(size_t)node * 2 + 0] = e0 * inv;
            out[(size_t)node * 2 + 1] = e1 * inv;
        }
    } else {
        constexpr int PER = (DOUT + 7) / 8;
        #pragma unroll
        for (int jj = 0; jj < PER; ++jj) {
            int j = q * PER + jj;
            if (j < DOUT)
                out[(size_t)node * DOUT + j] =
                    fmaxf(af[j] + oinit[(size_t)node * DOUT + j], 0.f);
        }
    }
}

// ---------------------------------------------------------------------------

extern "C" void kernel_launch(void* const* d_in, const int* in_sizes, int n_in,
                              void* d_out, int out_size, void* d_ws, size_t ws_size,
                              hipStream_t stream) {
    const float* x  = (const float*)d_in[0];
    const int*   ei = (const int*)d_in[1];
    const float* ew = (const float*)d_in[2];
    const float* wrel[5]  = { (const float*)d_in[3], (const float*)d_in[6],
                              (const float*)d_in[9], (const float*)d_in[12],
                              (const float*)d_in[15] };
    const float* brel[5]  = { (const float*)d_in[4], (const float*)d_in[7],
                              (const float*)d_in[10], (const float*)d_in[13],
                              (const float*)d_in[16] };
    const float* wroot[5] = { (const float*)d_in[5], (const float*)d_in[8],
                              (const float*)d_in[11], (const float*)d_in[14],
                              (const float*)d_in[17] };

    char* ws = (char*)d_ws;
    size_t off = 0;
    auto alloc = [&](size_t bytes) -> void* {
        void* ptr = ws + off;
        off += (bytes + 255) & ~(size_t)255;
        return ptr;
    };
    // region A: rec1 during sort; reused for p/oinit during layers
    char*     regionA   = (char*)alloc((size_t)N_EDGES * 8);          // 25.6 MB
    uint2*    rec1      = (uint2*)regionA;
    __half*   pbuf      = (__half*)regionA;                           // ≤ 3.2 MB
    float*    oinit     = (float*)(regionA + (size_t)8 * 1024 * 1024);// ≤ 6.0 MB
    uint32_t* rec2      = (uint32_t*)alloc((size_t)N_EDGES * 4);      // 12.8 MB
    __half*   xpad      = (__half*)alloc((size_t)N_NODES * 8 * 2);    // 1.6 MB
    // region B: hist_g+off_g during sort; fA+fB during layers
    char*     regionB   = (char*)alloc((size_t)14 * 1024 * 1024);
    int*      hist_g    = (int*)regionB;                              // 6.4 MB
    int*      off_g     = (int*)(regionB + (size_t)NCH_H * NB * 4);   // 6.4 MB
    float*    fA        = (float*)regionB;                            // 8.0 MB
    float*    fB        = (float*)(regionB + (size_t)8 * 1024 * 1024);// 6.0 MB
    int*      tot       = (int*)alloc((size_t)NB * 4);
    int*      bstart    = (int*)alloc((size_t)NB * 4);
    int*      row_start = (int*)alloc((size_t)N_NODES * 4);
    int*      cntb      = (int*)alloc((size_t)N_NODES * 4);

    const int* srcv = ei;            // edge_index row 0
    const int* dstv = ei + N_EDGES;  // edge_index row 1

    const int gN  = (N_NODES + BLOCK - 1) / BLOCK;          // 391
    const int gN8 = (8 * N_NODES + BLOCK - 1) / BLOCK;      // 3125

    pad_x_kernel    <<<gN, BLOCK, 0, stream>>>(x, xpad);
    hist_kernel     <<<NCH_H, BLOCK, 0, stream>>>(dstv, hist_g);
    chunkscan_kernel<<<(NB + 3) / 4, BLOCK, 0, stream>>>(hist_g, off_g, tot);
    scan_kernel     <<<1, SCAN_T, 0, stream>>>(tot, bstart);
    scatter1_kernel <<<NCH_S, BS1, 0, stream>>>(srcv, dstv, ew, bstart, off_g, rec1);
    scatter2_kernel <<<NB, BLOCK, 0, stream>>>(rec1, bstart, tot, rec2, row_start, cntb);

    // L0: 6 -> 20, aggregate pre-transform (fp16 gather of xpad)
    layer0_kernel<<<gN8, BLOCK, 0, stream>>>(xpad, rec2, row_start, cntb,
                                             wrel[0], brel[0], wroot[0], fA);
    // L1: 20 -> 15
    dense_kernel<20, 15, 16><<<gN, BLOCK, 0, stream>>>(fA, wrel[1], brel[1], wroot[1], pbuf, oinit);
    gather_kernel<15, 16, false><<<gN8, BLOCK, 0, stream>>>(pbuf, oinit, rec2, row_start, cntb, fB);
    // L2: 15 -> 10
    dense_kernel<15, 10, 16><<<gN, BLOCK, 0, stream>>>(fB, wrel[2], brel[2], wroot[2], pbuf, oinit);
    gather_kernel<10, 16, false><<<gN8, BLOCK, 0, stream>>>(pbuf, oinit, rec2, row_start, cntb, fA);
    // L3: 10 -> 5
    dense_kernel<10, 5, 8><<<gN, BLOCK, 0, stream>>>(fA, wrel[3], brel[3], wroot[3], pbuf, oinit);
    gather_kernel<5, 8, false><<<gN8, BLOCK, 0, stream>>>(pbuf, oinit, rec2, row_start, cntb, fB);
    // L4: 5 -> 2, softmax
    dense_kernel<5, 2, 2><<<gN, BLOCK, 0, stream>>>(fB, wrel[4], brel[4], wroot[4], pbuf, oinit);
    gather_kernel<2, 2, true><<<gN8, BLOCK, 0, stream>>>(pbuf, oinit, rec2, row_start, cntb, (float*)d_out);
}

// Round 8
// 330.493 us; speedup vs baseline: 5.0322x; 1.0379x over previous
//
#include <hip/hip_runtime.h>
#include <hip/hip_fp16.h>
#include <stdint.h>

#define N_NODES 100000
#define N_EDGES 3200000
#define BN      64                    // nodes per dst-bucket
#define NB      1563                  // ceil(N_NODES / BN)
// histogram granularity (fine)
#define NCH_H   1024
#define CH_H    (N_EDGES / NCH_H)     // 3125
#define CPL     (NCH_H / 64)          // 16 chunks per lane in chunkscan
#define PAD_PER 98                    // nodes padded per hist block (98*1024 >= N)
// scatter granularity (coarse, for long coalesced runs)
#define NCH_S   256
#define CH_S    (N_EDGES / NCH_S)     // 12500
#define BS1     1024                  // scatter1 block size
#define S1_IT   ((CH_S + BS1 - 1) / BS1)
#define S2_CAP  2560                  // scatter2 LDS stage capacity
#define BLOCK   256
#define W_SCALE 32767.0f
#define W_INV   (1.0f / 32767.0f)

// ---------------------------------------------------------------------------
// Stage 1: per-subchunk bucket histogram + fused x->fp16 padding
// ---------------------------------------------------------------------------
__global__ void hist_kernel(const int* __restrict__ dst, int* __restrict__ hist_g,
                            const float* __restrict__ x, __half* __restrict__ xpad) {
    __shared__ int h[NB];
    for (int b = threadIdx.x; b < NB; b += BLOCK) h[b] = 0;
    // fused pad: block c converts nodes [c*98, c*98+98)
    {
        int i = blockIdx.x * PAD_PER + threadIdx.x;
        if (threadIdx.x < PAD_PER && i < N_NODES) {
            const float* xr = x + (size_t)i * 6;
            __half2 hh[4];
            hh[0] = __halves2half2(__float2half(xr[0]), __float2half(xr[1]));
            hh[1] = __halves2half2(__float2half(xr[2]), __float2half(xr[3]));
            hh[2] = __halves2half2(__float2half(xr[4]), __float2half(xr[5]));
            hh[3] = __halves2half2(__float2half(0.f),   __float2half(0.f));
            *(uint4*)(xpad + (size_t)i * 8) = *(uint4*)hh;
        }
    }
    __syncthreads();
    const int c  = blockIdx.x;
    const int k0 = c * CH_H;
    for (int k = threadIdx.x; k < CH_H; k += BLOCK)
        atomicAdd(&h[dst[k0 + k] >> 6], 1);
    __syncthreads();
    for (int b = threadIdx.x; b < NB; b += BLOCK)
        hist_g[c * NB + b] = h[b];
}

// ---------------------------------------------------------------------------
// Stage 2a: per-bucket exclusive scan over the 1024 subchunk counts
// ---------------------------------------------------------------------------
__global__ void chunkscan_kernel(const int* __restrict__ hist_g,
                                 int* __restrict__ off_g, int* __restrict__ tot) {
    int w    = (blockIdx.x * blockDim.x + threadIdx.x) >> 6;
    int lane = threadIdx.x & 63;
    if (w >= NB) return;
    int v[CPL];
    int ls = 0;
    const int cbase = lane * CPL;
    #pragma unroll
    for (int i = 0; i < CPL; ++i) { v[i] = hist_g[(cbase + i) * NB + w]; ls += v[i]; }
    int run = ls;
    #pragma unroll
    for (int d = 1; d < 64; d <<= 1) {
        int u = __shfl_up(run, d);
        if (lane >= d) run += u;
    }
    int acc = run - ls;
    #pragma unroll
    for (int i = 0; i < CPL; ++i) { off_g[(cbase + i) * NB + w] = acc; acc += v[i]; }
    if (lane == 63) tot[w] = acc;
}

// ---------------------------------------------------------------------------
// Stage 2b: exclusive scan of 1563 bucket totals (one wg)
// ---------------------------------------------------------------------------
#define SCAN_T   1024
#define SCAN_PER 2
__global__ void scan_kernel(const int* __restrict__ cnt, int* __restrict__ bstart) {
    __shared__ int part[SCAN_T];
    int t = threadIdx.x;
    int local[SCAN_PER];
    int s = 0;
    #pragma unroll
    for (int i = 0; i < SCAN_PER; ++i) {
        int idx = t * SCAN_PER + i;
        int v = (idx < NB) ? cnt[idx] : 0;
        local[i] = s;
        s += v;
    }
    part[t] = s;
    __syncthreads();
    for (int off = 1; off < SCAN_T; off <<= 1) {
        int v = (t >= off) ? part[t - off] : 0;
        __syncthreads();
        part[t] += v;
        __syncthreads();
    }
    int excl = part[t] - s;
    #pragma unroll
    for (int i = 0; i < SCAN_PER; ++i) {
        int idx = t * SCAN_PER + i;
        if (idx < NB) bstart[idx] = excl + local[i];
    }
}

// ---------------------------------------------------------------------------
// Stage 3: scatter pass 1, stage-and-flush. Output split: recA = src|w15<<17
// (4 B, the final record payload) + recD = dl (1 B, scatter2-only key).
// Flush in stage order -> lane-contiguous full-line stores for both arrays.
// ---------------------------------------------------------------------------
__global__ void __launch_bounds__(BS1)
scatter1_kernel(const int* __restrict__ src, const int* __restrict__ dst,
                const float* __restrict__ w,
                const int* __restrict__ bstart, const int* __restrict__ off_g,
                uint32_t* __restrict__ recA, uint8_t* __restrict__ recD) {
    __shared__ uint32_t stage[CH_S];   // 50000 B
    __shared__ int h[NB];              // hist -> cursor
    __shared__ int delta[NB];          // global_base - local_start
    __shared__ int wtot[BS1 / 64];

    const int c  = blockIdx.x;
    const int k0 = c * CH_S;
    const int t  = threadIdx.x;

    // phase 1: histogram (cache dst in regs)
    for (int b = t; b < NB; b += BS1) h[b] = 0;
    __syncthreads();
    int dstv[S1_IT];
    int nit = 0;
    for (int k = t; k < CH_S; k += BS1, ++nit) {
        int d = dst[k0 + k];
        dstv[nit] = d;
        atomicAdd(&h[d >> 6], 1);
    }
    __syncthreads();

    // phase 2: block scan of h -> cursor start (in h) + delta
    {
        const int base = t * 2;          // 1024*2 = 2048 >= NB
        int v[2], ls = 0;
        #pragma unroll
        for (int i = 0; i < 2; ++i) {
            int idx = base + i;
            v[i] = (idx < NB) ? h[idx] : 0;
            ls += v[i];
        }
        int lane = t & 63, wv = t >> 6;
        int run = ls;
        #pragma unroll
        for (int d = 1; d < 64; d <<= 1) {
            int u = __shfl_up(run, d);
            if (lane >= d) run += u;
        }
        if (lane == 63) wtot[wv] = run;
        __syncthreads();
        int wexcl = 0;
        for (int i = 0; i < wv; ++i) wexcl += wtot[i];
        int excl = wexcl + run - ls;
        #pragma unroll
        for (int i = 0; i < 2; ++i) {
            int idx = base + i;
            if (idx < NB) {
                int gb = bstart[idx] + off_g[(size_t)(4 * c) * NB + idx];
                h[idx]     = excl;        // cursor (stage offset)
                delta[idx] = gb - excl;   // flush addr = delta[b] + stage_idx
                excl += v[i];
            }
        }
    }
    __syncthreads();

    // phase 3: scatter packed tokens into stage (LDS cursors)
    // token = le(14) | dl(6)<<14 | b(11)<<20
    nit = 0;
    for (int k = t; k < CH_S; k += BS1, ++nit) {
        int d = dstv[nit];
        int b = d >> 6;
        int pos = atomicAdd(&h[b], 1);
        stage[pos] = (uint32_t)k | ((uint32_t)(d & 63) << 14) | ((uint32_t)b << 20);
    }
    __syncthreads();

    // phase 4: flush in stage order -> lane-contiguous full-line stores
    for (int i = t; i < CH_S; i += BS1) {
        uint32_t sv = stage[i];
        int le = sv & 0x3FFF;
        int dl = (sv >> 14) & 0x3F;
        int b  = sv >> 20;
        int e  = k0 + le;
        uint32_t w15 = (uint32_t)__float2uint_rn(w[e] * W_SCALE);
        int pos = delta[b] + i;
        recA[pos] = (uint32_t)src[e] | (w15 << 17);
        recD[pos] = (uint8_t)dl;
    }
}

// ---------------------------------------------------------------------------
// Stage 4: scatter pass 2 — node-sort each bucket through an LDS stage.
// Reads recD (1 B) twice + recA (4 B) once; writes rec2 = recA permuted.
// ---------------------------------------------------------------------------
__global__ void scatter2_kernel(const uint32_t* __restrict__ recA,
                                const uint8_t* __restrict__ recD,
                                const int* __restrict__ bstart, const int* __restrict__ tot,
                                uint32_t* __restrict__ rec2,
                                int* __restrict__ row_start, int* __restrict__ cnt) {
    __shared__ int h[BN];
    __shared__ int cur[BN];
    __shared__ uint32_t stage[S2_CAP];
    const int b  = blockIdx.x;
    const int s0 = bstart[b];
    const int n  = tot[b];
    if (threadIdx.x < BN) h[threadIdx.x] = 0;
    __syncthreads();
    for (int k = threadIdx.x; k < n; k += BLOCK)
        atomicAdd(&h[recD[s0 + k]], 1);
    __syncthreads();
    if (threadIdx.x < BN) {
        int v = h[threadIdx.x];
        int run = v;
        #pragma unroll
        for (int d = 1; d < 64; d <<= 1) {
            int u = __shfl_up(run, d);
            if (threadIdx.x >= d) run += u;
        }
        int excl = run - v;
        cur[threadIdx.x] = excl;
        int node = b * BN + threadIdx.x;
        if (node < N_NODES) { row_start[node] = s0 + excl; cnt[node] = v; }
    }
    __syncthreads();
    for (int k = threadIdx.x; k < n; k += BLOCK) {
        uint32_t ra = recA[s0 + k];
        int dl = recD[s0 + k];
        int pos = atomicAdd(&cur[dl], 1);
        if (pos < S2_CAP) stage[pos] = ra;
        else              rec2[s0 + pos] = ra;  // overflow fallback (p ~ 0)
    }
    __syncthreads();
    for (int i = threadIdx.x; i < n && i < S2_CAP; i += BLOCK)
        rec2[s0 + i] = stage[i];                // coalesced full-line flush
}

// ---------------------------------------------------------------------------
// Layer 0 fused: aggregate xpad (din=6, fp16), out = relu(agg@Wrel0 + b0 +
// x@Wroot0)  [20], then directly emit L1 operands:
//   p1 = out@Wrel1 (fp16, SPH=16), oinit1 = out@Wroot1 + b1  [15]
// 8 lanes/node; all lanes hold the full vectors after the butterfly.
// ---------------------------------------------------------------------------
__global__ void layer0_kernel(const __half* __restrict__ xpad,
                              const uint32_t* __restrict__ rec,
                              const int* __restrict__ row_start, const int* __restrict__ cnt,
                              const float* __restrict__ wrel0, const float* __restrict__ brel0,
                              const float* __restrict__ wroot0,
                              const float* __restrict__ wrel1, const float* __restrict__ brel1,
                              const float* __restrict__ wroot1,
                              __half* __restrict__ pn, float* __restrict__ oinitn) {
    __shared__ float s_wrel0[6 * 20], s_wroot0[6 * 20], s_b0[20];
    __shared__ float s_wrel1[20 * 15], s_wroot1[20 * 15], s_b1[15];
    for (int t = threadIdx.x; t < 120; t += BLOCK) {
        s_wrel0[t]  = wrel0[t];
        s_wroot0[t] = wroot0[t];
    }
    for (int t = threadIdx.x; t < 300; t += BLOCK) {
        s_wrel1[t]  = wrel1[t];
        s_wroot1[t] = wroot1[t];
    }
    if (threadIdx.x < 20) s_b0[threadIdx.x] = brel0[threadIdx.x];
    else if (threadIdx.x >= 32 && threadIdx.x < 47) s_b1[threadIdx.x - 32] = brel1[threadIdx.x - 32];
    __syncthreads();

    int t = blockIdx.x * blockDim.x + threadIdx.x;
    int node = t >> 3;
    int q    = t & 7;

    float agg[6] = {0.f, 0.f, 0.f, 0.f, 0.f, 0.f};
    const int s = row_start[node];
    const int e = s + cnt[node];
    for (int k = s + q; k < e; k += 8) {
        uint32_t r = rec[k];
        float w = (float)(r >> 17) * W_INV;
        uint4 raw = *(const uint4*)(xpad + (size_t)(r & 0x1FFFF) * 8);
        const __half2* h = (const __half2*)&raw;
        agg[0] += w * __low2float(h[0]);  agg[1] += w * __high2float(h[0]);
        agg[2] += w * __low2float(h[1]);  agg[3] += w * __high2float(h[1]);
        agg[4] += w * __low2float(h[2]);  agg[5] += w * __high2float(h[2]);
    }
    #pragma unroll
    for (int i = 0; i < 6; ++i) {
        agg[i] += __shfl_xor(agg[i], 1);
        agg[i] += __shfl_xor(agg[i], 2);
        agg[i] += __shfl_xor(agg[i], 4);
    }
    uint4 raws = *(const uint4*)(xpad + (size_t)node * 8);
    const __half2* hs = (const __half2*)&raws;
    float xv[6] = { __low2float(hs[0]), __high2float(hs[0]),
                    __low2float(hs[1]), __high2float(hs[1]),
                    __low2float(hs[2]), __high2float(hs[2]) };

    float ov[20];
    #pragma unroll
    for (int j = 0; j < 20; ++j) {
        float o = s_b0[j];
        #pragma unroll
        for (int i = 0; i < 6; ++i)
            o += agg[i] * s_wrel0[i * 20 + j] + xv[i] * s_wroot0[i * 20 + j];
        ov[j] = fmaxf(o, 0.f);
    }

    // emit p1 pair (lane q -> halves 2q, 2q+1 of the 16-half row)
    {
        float pk[2] = {0.f, 0.f};
        #pragma unroll
        for (int kk = 0; kk < 2; ++kk) {
            int k = 2 * q + kk;
            if (k < 15) {
                float sacc = 0.f;
                #pragma unroll
                for (int j = 0; j < 20; ++j) sacc += ov[j] * s_wrel1[j * 15 + k];
                pk[kk] = sacc;
            }
        }
        ((__half2*)(pn + (size_t)node * 16))[q] =
            __halves2half2(__float2half(pk[0]), __float2half(pk[1]));
    }
    // emit oinit1 (lane q -> k = q, q+8)
    #pragma unroll
    for (int kk = 0; kk < 2; ++kk) {
        int k = q + kk * 8;
        if (k < 15) {
            float sacc = s_b1[k];
            #pragma unroll
            for (int j = 0; j < 20; ++j) sacc += ov[j] * s_wroot1[j * 15 + k];
            oinitn[(size_t)node * 15 + k] = sacc;
        }
    }
}

// ---------------------------------------------------------------------------
// Fused gather layer i: aggregate p_i, out = relu(agg + oinit_i), emit
// p_{i+1} (fp16) + oinit_{i+1}. LAST: softmax to out.
// ---------------------------------------------------------------------------
template<int DOUT, int SPH, int NDOUT, int NSPH, bool LAST>
__global__ void gather_kernel(const __half* __restrict__ p, const float* __restrict__ oinit,
                              const uint32_t* __restrict__ rec,
                              const int* __restrict__ row_start, const int* __restrict__ cnt,
                              const float* __restrict__ wrel_n, const float* __restrict__ brel_n,
                              const float* __restrict__ wroot_n,
                              __half* __restrict__ pn, float* __restrict__ oinitn,
                              float* __restrict__ out) {
    __shared__ float s_wrel[LAST ? 1 : DOUT * NDOUT];
    __shared__ float s_wroot[LAST ? 1 : DOUT * NDOUT];
    __shared__ float s_b[LAST ? 1 : (NDOUT > 0 ? NDOUT : 1)];
    if constexpr (!LAST) {
        for (int t = threadIdx.x; t < DOUT * NDOUT; t += BLOCK) {
            s_wrel[t]  = wrel_n[t];
            s_wroot[t] = wroot_n[t];
        }
        if (threadIdx.x < NDOUT) s_b[threadIdx.x] = brel_n[threadIdx.x];
        __syncthreads();
    }

    int t = blockIdx.x * blockDim.x + threadIdx.x;
    int node = t >> 3;
    int q    = t & 7;

    float af[SPH];
    #pragma unroll
    for (int i = 0; i < SPH; ++i) af[i] = 0.f;

    const int s = row_start[node];
    const int e = s + cnt[node];
    for (int k = s + q; k < e; k += 8) {
        uint32_t r = rec[k];
        float w = (float)(r >> 17) * W_INV;
        const __half* ps = p + (size_t)(r & 0x1FFFF) * SPH;
        if constexpr (SPH >= 8) {
            #pragma unroll
            for (int v = 0; v < SPH / 8; ++v) {
                uint4 raw = ((const uint4*)ps)[v];
                const __half2* h = (const __half2*)&raw;
                #pragma unroll
                for (int jj = 0; jj < 4; ++jj) {
                    af[v * 8 + 2 * jj]     += w * __low2float(h[jj]);
                    af[v * 8 + 2 * jj + 1] += w * __high2float(h[jj]);
                }
            }
        } else {
            uint32_t raw = *(const uint32_t*)ps;
            __half2 h = *(const __half2*)&raw;
            af[0] += w * __low2float(h);
            af[1] += w * __high2float(h);
        }
    }
    #pragma unroll
    for (int i = 0; i < SPH; ++i) {
        af[i] += __shfl_xor(af[i], 1);
        af[i] += __shfl_xor(af[i], 2);
        af[i] += __shfl_xor(af[i], 4);
    }

    if constexpr (LAST) {
        if (q == 0) {
            float o0 = af[0] + oinit[(size_t)node * 2 + 0];
            float o1 = af[1] + oinit[(size_t)node * 2 + 1];
            float m = fmaxf(o0, o1);
            float e0 = __expf(o0 - m), e1 = __expf(o1 - m);
            float inv = 1.f / (e0 + e1);
            out[(size_t)node * 2 + 0] = e0 * inv;
            out[(size_t)node * 2 + 1] = e1 * inv;
        }
    } else {
        float ov[DOUT];
        #pragma unroll
        for (int j = 0; j < DOUT; ++j)
            ov[j] = fmaxf(af[j] + oinit[(size_t)node * DOUT + j], 0.f);

        // emit p' pair (lane q -> halves 2q,2q+1) — covers all NSPH halves
        if (q < NSPH / 2) {
            float pk[2] = {0.f, 0.f};
            #pragma unroll
            for (int kk = 0; kk < 2; ++kk) {
                int k = 2 * q + kk;
                if (k < NDOUT) {
                    float sacc = 0.f;
                    #pragma unroll
                    for (int j = 0; j < DOUT; ++j) sacc += ov[j] * s_wrel[j * NDOUT + k];
                    pk[kk] = sacc;
                }
            }
            ((__half2*)(pn + (size_t)node * NSPH))[q] =
                __halves2half2(__float2half(pk[0]), __float2half(pk[1]));
        }
        // emit oinit' (lane q -> k = q, q+8)
        #pragma unroll
        for (int kk = 0; kk < 2; ++kk) {
            int k = q + kk * 8;
            if (k < NDOUT) {
                float sacc = s_b[k];
                #pragma unroll
                for (int j = 0; j < DOUT; ++j) sacc += ov[j] * s_wroot[j * NDOUT + k];
                oinitn[(size_t)node * NDOUT + k] = sacc;
            }
        }
    }
}

// ---------------------------------------------------------------------------

extern "C" void kernel_launch(void* const* d_in, const int* in_sizes, int n_in,
                              void* d_out, int out_size, void* d_ws, size_t ws_size,
                              hipStream_t stream) {
    const float* x  = (const float*)d_in[0];
    const int*   ei = (const int*)d_in[1];
    const float* ew = (const float*)d_in[2];
    const float* wrel[5]  = { (const float*)d_in[3], (const float*)d_in[6],
                              (const float*)d_in[9], (const float*)d_in[12],
                              (const float*)d_in[15] };
    const float* brel[5]  = { (const float*)d_in[4], (const float*)d_in[7],
                              (const float*)d_in[10], (const float*)d_in[13],
                              (const float*)d_in[16] };
    const float* wroot[5] = { (const float*)d_in[5], (const float*)d_in[8],
                              (const float*)d_in[11], (const float*)d_in[14],
                              (const float*)d_in[17] };

    char* ws = (char*)d_ws;
    size_t off = 0;
    auto alloc = [&](size_t bytes) -> void* {
        void* ptr = ws + off;
        off += (bytes + 255) & ~(size_t)255;
        return ptr;
    };
    uint32_t* recA      = (uint32_t*)alloc((size_t)N_EDGES * 4);      // 12.8 MB
    uint8_t*  recD      = (uint8_t*)alloc((size_t)N_EDGES);           // 3.2 MB
    uint32_t* rec2      = (uint32_t*)alloc((size_t)N_EDGES * 4);      // 12.8 MB
    __half*   xpad      = (__half*)alloc((size_t)N_NODES * 8 * 2);    // 1.6 MB
    // regionB: hist_g+off_g during sort (12.8 MB); p/oinit dbuf during layers (18.4 MB)
    char*     regionB   = (char*)alloc((size_t)19 * 1024 * 1024);
    int*      hist_g    = (int*)regionB;                              // 6.4 MB
    int*      off_g     = (int*)(regionB + (size_t)NCH_H * NB * 4);   // 6.4 MB
    __half*   pA        = (__half*)regionB;                           // 3.2 MB
    __half*   pB        = (__half*)(regionB + (size_t)4 * 1024 * 1024);
    float*    oA        = (float*)(regionB + (size_t)8 * 1024 * 1024);  // 6 MB
    float*    oB        = (float*)(regionB + (size_t)14 * 1024 * 1024); // 6 MB... 14+6=20>19? fix below
    int*      tot       = (int*)alloc((size_t)NB * 4);
    int*      bstart    = (int*)alloc((size_t)NB * 4);
    int*      row_start = (int*)alloc((size_t)N_NODES * 4);
    int*      cntb      = (int*)alloc((size_t)N_NODES * 4);
    float*    oB2       = (float*)alloc((size_t)N_NODES * 15 * 4);    // separate 6 MB for oB
    oB = oB2;

    const int* srcv = ei;            // edge_index row 0
    const int* dstv = ei + N_EDGES;  // edge_index row 1

    const int gN8 = (8 * N_NODES + BLOCK - 1) / BLOCK;      // 3125

    hist_kernel     <<<NCH_H, BLOCK, 0, stream>>>(dstv, hist_g, x, xpad);
    chunkscan_kernel<<<(NB + 3) / 4, BLOCK, 0, stream>>>(hist_g, off_g, tot);
    scan_kernel     <<<1, SCAN_T, 0, stream>>>(tot, bstart);
    scatter1_kernel <<<NCH_S, BS1, 0, stream>>>(srcv, dstv, ew, bstart, off_g, recA, recD);
    scatter2_kernel <<<NB, BLOCK, 0, stream>>>(recA, recD, bstart, tot, rec2, row_start, cntb);

    // L0 fused: 6 -> 20 (relu) -> emit p1 [15, SPH 16] + oinit1
    layer0_kernel<<<gN8, BLOCK, 0, stream>>>(xpad, rec2, row_start, cntb,
                                             wrel[0], brel[0], wroot[0],
                                             wrel[1], brel[1], wroot[1], pA, oA);
    // g1: agg p1, out1 [15] -> p2 [10, SPH 16] + oinit2
    gather_kernel<15, 16, 10, 16, false><<<gN8, BLOCK, 0, stream>>>(
        pA, oA, rec2, row_start, cntb, wrel[2], brel[2], wroot[2], pB, oB, nullptr);
    // g2: agg p2, out2 [10] -> p3 [5, SPH 8] + oinit3
    gather_kernel<10, 16, 5, 8, false><<<gN8, BLOCK, 0, stream>>>(
        pB, oB, rec2, row_start, cntb, wrel[3], brel[3], wroot[3], pA, oA, nullptr);
    // g3: agg p3, out3 [5] -> p4 [2, SPH 2] + oinit4
    gather_kernel<5, 8, 2, 2, false><<<gN8, BLOCK, 0, stream>>>(
        pA, oA, rec2, row_start, cntb, wrel[4], brel[4], wroot[4], pB, oB, nullptr);
    // g4: agg p4, softmax -> d_out
    gather_kernel<2, 2, 0, 0, true><<<gN8, BLOCK, 0, stream>>>(
        pB, oB, rec2, row_start, cntb, nullptr, nullptr, nullptr,
        nullptr, nullptr, (float*)d_out);
}

// Round 9
// 322.719 us; speedup vs baseline: 5.1534x; 1.0241x over previous
//
#include <hip/hip_runtime.h>
#include <hip/hip_fp16.h>
#include <stdint.h>

#define N_NODES 100000
#define N_EDGES 3200000
#define BN      64                    // nodes per dst-bucket
#define NB      1563                  // ceil(N_NODES / BN)
// histogram granularity (fine)
#define NCH_H   1024
#define CH_H    (N_EDGES / NCH_H)     // 3125
#define CPL     (NCH_H / 64)          // 16 chunks per lane in chunkscan
#define PAD_PER 98                    // nodes padded per hist block
// scatter granularity (coarse, for long coalesced runs)
#define NCH_S   256
#define CH_S    (N_EDGES / NCH_S)     // 12500
#define BS1     1024                  // scatter1 block size
#define S1_IT   ((CH_S + BS1 - 1) / BS1)
#define S2_CAP  2560                  // scatter2 LDS stage capacity
#define BLOCK   256
#define W_SCALE 32767.0f
#define W_INV   (1.0f / 32767.0f)

// ---------------------------------------------------------------------------
// Stage 1: per-subchunk bucket histogram + fused x->fp16 padding
// ---------------------------------------------------------------------------
__global__ void hist_kernel(const int* __restrict__ dst, int* __restrict__ hist_g,
                            const float* __restrict__ x, __half* __restrict__ xpad) {
    __shared__ int h[NB];
    for (int b = threadIdx.x; b < NB; b += BLOCK) h[b] = 0;
    {
        int i = blockIdx.x * PAD_PER + threadIdx.x;
        if (threadIdx.x < PAD_PER && i < N_NODES) {
            const float* xr = x + (size_t)i * 6;
            __half2 hh[4];
            hh[0] = __halves2half2(__float2half(xr[0]), __float2half(xr[1]));
            hh[1] = __halves2half2(__float2half(xr[2]), __float2half(xr[3]));
            hh[2] = __halves2half2(__float2half(xr[4]), __float2half(xr[5]));
            hh[3] = __halves2half2(__float2half(0.f),   __float2half(0.f));
            *(uint4*)(xpad + (size_t)i * 8) = *(uint4*)hh;
        }
    }
    __syncthreads();
    const int c  = blockIdx.x;
    const int k0 = c * CH_H;
    for (int k = threadIdx.x; k < CH_H; k += BLOCK)
        atomicAdd(&h[dst[k0 + k] >> 6], 1);
    __syncthreads();
    for (int b = threadIdx.x; b < NB; b += BLOCK)
        hist_g[c * NB + b] = h[b];
}

// ---------------------------------------------------------------------------
// Stage 2a: per-bucket exclusive scan over the 1024 subchunk counts
// ---------------------------------------------------------------------------
__global__ void chunkscan_kernel(const int* __restrict__ hist_g,
                                 int* __restrict__ off_g, int* __restrict__ tot) {
    int w    = (blockIdx.x * blockDim.x + threadIdx.x) >> 6;
    int lane = threadIdx.x & 63;
    if (w >= NB) return;
    int v[CPL];
    int ls = 0;
    const int cbase = lane * CPL;
    #pragma unroll
    for (int i = 0; i < CPL; ++i) { v[i] = hist_g[(cbase + i) * NB + w]; ls += v[i]; }
    int run = ls;
    #pragma unroll
    for (int d = 1; d < 64; d <<= 1) {
        int u = __shfl_up(run, d);
        if (lane >= d) run += u;
    }
    int acc = run - ls;
    #pragma unroll
    for (int i = 0; i < CPL; ++i) { off_g[(cbase + i) * NB + w] = acc; acc += v[i]; }
    if (lane == 63) tot[w] = acc;
}

// ---------------------------------------------------------------------------
// Stage 2b: exclusive scan of 1563 bucket totals (one wg)
// ---------------------------------------------------------------------------
#define SCAN_T   1024
#define SCAN_PER 2
__global__ void scan_kernel(const int* __restrict__ cnt, int* __restrict__ bstart) {
    __shared__ int part[SCAN_T];
    int t = threadIdx.x;
    int local[SCAN_PER];
    int s = 0;
    #pragma unroll
    for (int i = 0; i < SCAN_PER; ++i) {
        int idx = t * SCAN_PER + i;
        int v = (idx < NB) ? cnt[idx] : 0;
        local[i] = s;
        s += v;
    }
    part[t] = s;
    __syncthreads();
    for (int off = 1; off < SCAN_T; off <<= 1) {
        int v = (t >= off) ? part[t - off] : 0;
        __syncthreads();
        part[t] += v;
        __syncthreads();
    }
    int excl = part[t] - s;
    #pragma unroll
    for (int i = 0; i < SCAN_PER; ++i) {
        int idx = t * SCAN_PER + i;
        if (idx < NB) bstart[idx] = excl + local[i];
    }
}

// ---------------------------------------------------------------------------
// Stage 3: scatter pass 1, stage-and-flush (8 B records, R7-proven).
// rec1: x = src(17) | dl(6)<<17 ; y = weight fp32 bits.
// ---------------------------------------------------------------------------
__global__ void __launch_bounds__(BS1)
scatter1_kernel(const int* __restrict__ src, const int* __restrict__ dst,
                const float* __restrict__ w,
                const int* __restrict__ bstart, const int* __restrict__ off_g,
                uint2* __restrict__ rec1) {
    __shared__ uint32_t stage[CH_S];   // 50000 B
    __shared__ int h[NB];
    __shared__ int delta[NB];
    __shared__ int wtot[BS1 / 64];

    const int c  = blockIdx.x;
    const int k0 = c * CH_S;
    const int t  = threadIdx.x;

    for (int b = t; b < NB; b += BS1) h[b] = 0;
    __syncthreads();
    int dstv[S1_IT];
    int nit = 0;
    for (int k = t; k < CH_S; k += BS1, ++nit) {
        int d = dst[k0 + k];
        dstv[nit] = d;
        atomicAdd(&h[d >> 6], 1);
    }
    __syncthreads();

    {
        const int base = t * 2;          // 2048 >= NB
        int v[2], ls = 0;
        #pragma unroll
        for (int i = 0; i < 2; ++i) {
            int idx = base + i;
            v[i] = (idx < NB) ? h[idx] : 0;
            ls += v[i];
        }
        int lane = t & 63, wv = t >> 6;
        int run = ls;
        #pragma unroll
        for (int d = 1; d < 64; d <<= 1) {
            int u = __shfl_up(run, d);
            if (lane >= d) run += u;
        }
        if (lane == 63) wtot[wv] = run;
        __syncthreads();
        int wexcl = 0;
        for (int i = 0; i < wv; ++i) wexcl += wtot[i];
        int excl = wexcl + run - ls;
        #pragma unroll
        for (int i = 0; i < 2; ++i) {
            int idx = base + i;
            if (idx < NB) {
                int gb = bstart[idx] + off_g[(size_t)(4 * c) * NB + idx];
                h[idx]     = excl;
                delta[idx] = gb - excl;
                excl += v[i];
            }
        }
    }
    __syncthreads();

    // token = le(14) | dl(6)<<14 | b(11)<<20
    nit = 0;
    for (int k = t; k < CH_S; k += BS1, ++nit) {
        int d = dstv[nit];
        int b = d >> 6;
        int pos = atomicAdd(&h[b], 1);
        stage[pos] = (uint32_t)k | ((uint32_t)(d & 63) << 14) | ((uint32_t)b << 20);
    }
    __syncthreads();

    for (int i = t; i < CH_S; i += BS1) {
        uint32_t sv = stage[i];
        int le = sv & 0x3FFF;
        int dl = (sv >> 14) & 0x3F;
        int b  = sv >> 20;
        int e  = k0 + le;
        uint2 r;
        r.x = (uint32_t)src[e] | ((uint32_t)dl << 17);
        r.y = __float_as_uint(w[e]);
        rec1[delta[b] + i] = r;
    }
}

// ---------------------------------------------------------------------------
// Stage 4: scatter pass 2 — node-sort each bucket through an LDS stage.
// Emits 4 B rec2 = src(17) | w15(15)<<17.
// ---------------------------------------------------------------------------
__global__ void scatter2_kernel(const uint2* __restrict__ rec1,
                                const int* __restrict__ bstart, const int* __restrict__ tot,
                                uint32_t* __restrict__ rec2,
                                int* __restrict__ row_start, int* __restrict__ cnt) {
    __shared__ int h[BN];
    __shared__ int cur[BN];
    __shared__ uint32_t stage[S2_CAP];
    const int b  = blockIdx.x;
    const int s0 = bstart[b];
    const int n  = tot[b];
    if (threadIdx.x < BN) h[threadIdx.x] = 0;
    __syncthreads();
    for (int k = threadIdx.x; k < n; k += BLOCK)
        atomicAdd(&h[rec1[s0 + k].x >> 17], 1);
    __syncthreads();
    if (threadIdx.x < BN) {
        int v = h[threadIdx.x];
        int run = v;
        #pragma unroll
        for (int d = 1; d < 64; d <<= 1) {
            int u = __shfl_up(run, d);
            if (threadIdx.x >= d) run += u;
        }
        int excl = run - v;
        cur[threadIdx.x] = excl;
        int node = b * BN + threadIdx.x;
        if (node < N_NODES) { row_start[node] = s0 + excl; cnt[node] = v; }
    }
    __syncthreads();
    for (int k = threadIdx.x; k < n; k += BLOCK) {
        uint2 r = rec1[s0 + k];
        int dl = (int)(r.x >> 17);
        float wv = __uint_as_float(r.y);
        uint32_t w15 = (uint32_t)__float2uint_rn(wv * W_SCALE);
        uint32_t r2 = (r.x & 0x1FFFF) | (w15 << 17);
        int pos = atomicAdd(&cur[dl], 1);
        if (pos < S2_CAP) stage[pos] = r2;
        else              rec2[s0 + pos] = r2;
    }
    __syncthreads();
    for (int i = threadIdx.x; i < n && i < S2_CAP; i += BLOCK)
        rec2[s0 + i] = stage[i];
}

// ---------------------------------------------------------------------------
// Layer 0 fused: aggregate xpad (6, fp16) with batched loads, relu,
// emit p1 (fp16) + oinit1. 8 lanes/node.
// ---------------------------------------------------------------------------
__global__ void layer0_kernel(const __half* __restrict__ xpad,
                              const uint32_t* __restrict__ rec,
                              const int* __restrict__ row_start, const int* __restrict__ cnt,
                              const float* __restrict__ wrel0, const float* __restrict__ brel0,
                              const float* __restrict__ wroot0,
                              const float* __restrict__ wrel1, const float* __restrict__ brel1,
                              const float* __restrict__ wroot1,
                              __half* __restrict__ pn, float* __restrict__ oinitn) {
    __shared__ float s_wrel0[6 * 20], s_wroot0[6 * 20], s_b0[20];
    __shared__ float s_wrel1[20 * 15], s_wroot1[20 * 15], s_b1[15];
    for (int t = threadIdx.x; t < 120; t += BLOCK) {
        s_wrel0[t]  = wrel0[t];
        s_wroot0[t] = wroot0[t];
    }
    for (int t = threadIdx.x; t < 300; t += BLOCK) {
        s_wrel1[t]  = wrel1[t];
        s_wroot1[t] = wroot1[t];
    }
    if (threadIdx.x < 20) s_b0[threadIdx.x] = brel0[threadIdx.x];
    if (threadIdx.x < 15) s_b1[threadIdx.x] = brel1[threadIdx.x];
    __syncthreads();

    int t = blockIdx.x * blockDim.x + threadIdx.x;
    int node = t >> 3;
    int q    = t & 7;

    float agg[6] = {0.f, 0.f, 0.f, 0.f, 0.f, 0.f};
    const int s = row_start[node];
    const int e = s + cnt[node];
    // batched: 4 rec loads -> 4 row loads -> accumulate (2 latency rounds/batch)
    for (int k = s + q; k < e; k += 32) {
        uint32_t rv[4];
        float    wv[4];
        #pragma unroll
        for (int u = 0; u < 4; ++u) {
            int kk = k + 8 * u;
            int kc = kk < e ? kk : (e - 1);
            rv[u] = rec[kc];
            wv[u] = kk < e ? (float)(rv[u] >> 17) * W_INV : 0.f;
        }
        uint4 raw[4];
        #pragma unroll
        for (int u = 0; u < 4; ++u)
            raw[u] = *(const uint4*)(xpad + (size_t)(rv[u] & 0x1FFFF) * 8);
        #pragma unroll
        for (int u = 0; u < 4; ++u) {
            const __half2* h = (const __half2*)&raw[u];
            float w = wv[u];
            agg[0] += w * __low2float(h[0]);  agg[1] += w * __high2float(h[0]);
            agg[2] += w * __low2float(h[1]);  agg[3] += w * __high2float(h[1]);
            agg[4] += w * __low2float(h[2]);  agg[5] += w * __high2float(h[2]);
        }
    }
    #pragma unroll
    for (int i = 0; i < 6; ++i) {
        agg[i] += __shfl_xor(agg[i], 1);
        agg[i] += __shfl_xor(agg[i], 2);
        agg[i] += __shfl_xor(agg[i], 4);
    }
    uint4 raws = *(const uint4*)(xpad + (size_t)node * 8);
    const __half2* hs = (const __half2*)&raws;
    float xv[6] = { __low2float(hs[0]), __high2float(hs[0]),
                    __low2float(hs[1]), __high2float(hs[1]),
                    __low2float(hs[2]), __high2float(hs[2]) };

    float ov[20];
    #pragma unroll
    for (int j = 0; j < 20; ++j) {
        float o = s_b0[j];
        #pragma unroll
        for (int i = 0; i < 6; ++i)
            o += agg[i] * s_wrel0[i * 20 + j] + xv[i] * s_wroot0[i * 20 + j];
        ov[j] = fmaxf(o, 0.f);
    }

    {
        float pk[2] = {0.f, 0.f};
        #pragma unroll
        for (int kk = 0; kk < 2; ++kk) {
            int k = 2 * q + kk;
            if (k < 15) {
                float sacc = 0.f;
                #pragma unroll
                for (int j = 0; j < 20; ++j) sacc += ov[j] * s_wrel1[j * 15 + k];
                pk[kk] = sacc;
            }
        }
        ((__half2*)(pn + (size_t)node * 16))[q] =
            __halves2half2(__float2half(pk[0]), __float2half(pk[1]));
    }
    #pragma unroll
    for (int kk = 0; kk < 2; ++kk) {
        int k = q + kk * 8;
        if (k < 15) {
            float sacc = s_b1[k];
            #pragma unroll
            for (int j = 0; j < 20; ++j) sacc += ov[j] * s_wroot1[j * 15 + k];
            oinitn[(size_t)node * 15 + k] = sacc;
        }
    }
}

// ---------------------------------------------------------------------------
// Fused gather layer: batched aggregate p_i, out = relu(agg + oinit_i),
// emit p_{i+1} + oinit_{i+1}. LAST: softmax.
// ---------------------------------------------------------------------------
template<int DOUT, int SPH, int NDOUT, int NSPH, bool LAST>
__global__ void gather_kernel(const __half* __restrict__ p, const float* __restrict__ oinit,
                              const uint32_t* __restrict__ rec,
                              const int* __restrict__ row_start, const int* __restrict__ cnt,
                              const float* __restrict__ wrel_n, const float* __restrict__ brel_n,
                              const float* __restrict__ wroot_n,
                              __half* __restrict__ pn, float* __restrict__ oinitn,
                              float* __restrict__ out) {
    __shared__ float s_wrel[LAST ? 1 : DOUT * NDOUT];
    __shared__ float s_wroot[LAST ? 1 : DOUT * NDOUT];
    __shared__ float s_b[LAST ? 1 : (NDOUT > 0 ? NDOUT : 1)];
    if constexpr (!LAST) {
        for (int t = threadIdx.x; t < DOUT * NDOUT; t += BLOCK) {
            s_wrel[t]  = wrel_n[t];
            s_wroot[t] = wroot_n[t];
        }
        if (threadIdx.x < NDOUT) s_b[threadIdx.x] = brel_n[threadIdx.x];
        __syncthreads();
    }

    int t = blockIdx.x * blockDim.x + threadIdx.x;
    int node = t >> 3;
    int q    = t & 7;

    float af[SPH];
    #pragma unroll
    for (int i = 0; i < SPH; ++i) af[i] = 0.f;

    const int s = row_start[node];
    const int e = s + cnt[node];
    constexpr int NR = (SPH >= 8) ? SPH / 8 : 1;   // uint4 rows per edge (SPH=2 -> uint32)
    for (int k = s + q; k < e; k += 32) {
        uint32_t rv[4];
        float    wv[4];
        #pragma unroll
        for (int u = 0; u < 4; ++u) {
            int kk = k + 8 * u;
            int kc = kk < e ? kk : (e - 1);
            rv[u] = rec[kc];
            wv[u] = kk < e ? (float)(rv[u] >> 17) * W_INV : 0.f;
        }
        if constexpr (SPH >= 8) {
            uint4 raw[4 * NR];
            #pragma unroll
            for (int u = 0; u < 4; ++u) {
                const uint4* ps = (const uint4*)(p + (size_t)(rv[u] & 0x1FFFF) * SPH);
                #pragma unroll
                for (int v = 0; v < NR; ++v) raw[u * NR + v] = ps[v];
            }
            #pragma unroll
            for (int u = 0; u < 4; ++u) {
                float w = wv[u];
                #pragma unroll
                for (int v = 0; v < NR; ++v) {
                    const __half2* h = (const __half2*)&raw[u * NR + v];
                    #pragma unroll
                    for (int jj = 0; jj < 4; ++jj) {
                        af[v * 8 + 2 * jj]     += w * __low2float(h[jj]);
                        af[v * 8 + 2 * jj + 1] += w * __high2float(h[jj]);
                    }
                }
            }
        } else {
            uint32_t raw[4];
            #pragma unroll
            for (int u = 0; u < 4; ++u)
                raw[u] = *(const uint32_t*)(p + (size_t)(rv[u] & 0x1FFFF) * SPH);
            #pragma unroll
            for (int u = 0; u < 4; ++u) {
                __half2 h = *(const __half2*)&raw[u];
                af[0] += wv[u] * __low2float(h);
                af[1] += wv[u] * __high2float(h);
            }
        }
    }
    #pragma unroll
    for (int i = 0; i < SPH; ++i) {
        af[i] += __shfl_xor(af[i], 1);
        af[i] += __shfl_xor(af[i], 2);
        af[i] += __shfl_xor(af[i], 4);
    }

    if constexpr (LAST) {
        if (q == 0) {
            float o0 = af[0] + oinit[(size_t)node * 2 + 0];
            float o1 = af[1] + oinit[(size_t)node * 2 + 1];
            float m = fmaxf(o0, o1);
            float e0 = __expf(o0 - m), e1 = __expf(o1 - m);
            float inv = 1.f / (e0 + e1);
            out[(size_t)node * 2 + 0] = e0 * inv;
            out[(size_t)node * 2 + 1] = e1 * inv;
        }
    } else {
        float ov[DOUT];
        #pragma unroll
        for (int j = 0; j < DOUT; ++j)
            ov[j] = fmaxf(af[j] + oinit[(size_t)node * DOUT + j], 0.f);

        if (q < NSPH / 2) {
            float pk[2] = {0.f, 0.f};
            #pragma unroll
            for (int kk = 0; kk < 2; ++kk) {
                int k = 2 * q + kk;
                if (k < NDOUT) {
                    float sacc = 0.f;
                    #pragma unroll
                    for (int j = 0; j < DOUT; ++j) sacc += ov[j] * s_wrel[j * NDOUT + k];
                    pk[kk] = sacc;
                }
            }
            ((__half2*)(pn + (size_t)node * NSPH))[q] =
                __halves2half2(__float2half(pk[0]), __float2half(pk[1]));
        }
        #pragma unroll
        for (int kk = 0; kk < 2; ++kk) {
            int k = q + kk * 8;
            if (k < NDOUT) {
                float sacc = s_b[k];
                #pragma unroll
                for (int j = 0; j < DOUT; ++j) sacc += ov[j] * s_wroot[j * NDOUT + k];
                oinitn[(size_t)node * NDOUT + k] = sacc;
            }
        }
    }
}

// ---------------------------------------------------------------------------

extern "C" void kernel_launch(void* const* d_in, const int* in_sizes, int n_in,
                              void* d_out, int out_size, void* d_ws, size_t ws_size,
                              hipStream_t stream) {
    const float* x  = (const float*)d_in[0];
    const int*   ei = (const int*)d_in[1];
    const float* ew = (const float*)d_in[2];
    const float* wrel[5]  = { (const float*)d_in[3], (const float*)d_in[6],
                              (const float*)d_in[9], (const float*)d_in[12],
                              (const float*)d_in[15] };
    const float* brel[5]  = { (const float*)d_in[4], (const float*)d_in[7],
                              (const float*)d_in[10], (const float*)d_in[13],
                              (const float*)d_in[16] };
    const float* wroot[5] = { (const float*)d_in[5], (const float*)d_in[8],
                              (const float*)d_in[11], (const float*)d_in[14],
                              (const float*)d_in[17] };

    char* ws = (char*)d_ws;
    size_t off = 0;
    auto alloc = [&](size_t bytes) -> void* {
        void* ptr = ws + off;
        off += (bytes + 255) & ~(size_t)255;
        return ptr;
    };
    // regionA: rec1 during sort (25.6 MB); p/oinit ping-pong during layers
    char*     regionA   = (char*)alloc((size_t)N_EDGES * 8);
    uint2*    rec1      = (uint2*)regionA;
    __half*   pA        = (__half*)regionA;                              // 3.2 MB
    __half*   pB        = (__half*)(regionA + (size_t)4  * 1024 * 1024); // 3.2 MB
    float*    oA        = (float*)(regionA + (size_t)8  * 1024 * 1024);  // 6 MB
    float*    oB        = (float*)(regionA + (size_t)16 * 1024 * 1024);  // 6 MB
    uint32_t* rec2      = (uint32_t*)alloc((size_t)N_EDGES * 4);         // 12.8 MB
    __half*   xpad      = (__half*)alloc((size_t)N_NODES * 8 * 2);       // 1.6 MB
    // regionB: hist_g + off_g during sort only
    int*      hist_g    = (int*)alloc((size_t)NCH_H * NB * 4);           // 6.4 MB
    int*      off_g     = (int*)alloc((size_t)NCH_H * NB * 4);           // 6.4 MB
    int*      tot       = (int*)alloc((size_t)NB * 4);
    int*      bstart    = (int*)alloc((size_t)NB * 4);
    int*      row_start = (int*)alloc((size_t)N_NODES * 4);
    int*      cntb      = (int*)alloc((size_t)N_NODES * 4);

    const int* srcv = ei;            // edge_index row 0
    const int* dstv = ei + N_EDGES;  // edge_index row 1

    const int gN8 = (8 * N_NODES + BLOCK - 1) / BLOCK;      // 3125

    hist_kernel     <<<NCH_H, BLOCK, 0, stream>>>(dstv, hist_g, x, xpad);
    chunkscan_kernel<<<(NB + 3) / 4, BLOCK, 0, stream>>>(hist_g, off_g, tot);
    scan_kernel     <<<1, SCAN_T, 0, stream>>>(tot, bstart);
    scatter1_kernel <<<NCH_S, BS1, 0, stream>>>(srcv, dstv, ew, bstart, off_g, rec1);
    scatter2_kernel <<<NB, BLOCK, 0, stream>>>(rec1, bstart, tot, rec2, row_start, cntb);

    // L0 fused: 6 -> 20 (relu) -> emit p1 [15, SPH 16] + oinit1
    layer0_kernel<<<gN8, BLOCK, 0, stream>>>(xpad, rec2, row_start, cntb,
                                             wrel[0], brel[0], wroot[0],
                                             wrel[1], brel[1], wroot[1], pA, oA);
    // g1: agg p1, out1 [15] -> p2 [10, SPH 16] + oinit2
    gather_kernel<15, 16, 10, 16, false><<<gN8, BLOCK, 0, stream>>>(
        pA, oA, rec2, row_start, cntb, wrel[2], brel[2], wroot[2], pB, oB, nullptr);
    // g2: agg p2, out2 [10] -> p3 [5, SPH 8] + oinit3
    gather_kernel<10, 16, 5, 8, false><<<gN8, BLOCK, 0, stream>>>(
        pB, oB, rec2, row_start, cntb, wrel[3], brel[3], wroot[3], pA, oA, nullptr);
    // g3: agg p3, out3 [5] -> p4 [2, SPH 2] + oinit4
    gather_kernel<5, 8, 2, 2, false><<<gN8, BLOCK, 0, stream>>>(
        pA, oA, rec2, row_start, cntb, wrel[4], brel[4], wroot[4], pB, oB, nullptr);
    // g4: agg p4, softmax -> d_out
    gather_kernel<2, 2, 0, 0, true><<<gN8, BLOCK, 0, stream>>>(
        pB, oB, rec2, row_start, cntb, nullptr, nullptr, nullptr,
        nullptr, nullptr, (float*)d_out);
}